// Round 5
// baseline (415.397 us; speedup 1.0000x reference)
//
#include <hip/hip_runtime.h>
#include <hip/hip_bf16.h>
#include <math.h>

#define H1 100
#define H2 16
#define FDIM 256
#define NPAD 112   // H1 padded to 7*16

typedef __attribute__((ext_vector_type(8))) short bf16x8;
typedef __attribute__((ext_vector_type(4))) float f32x4;

// ---- bf16 pack/unpack helpers (bit-exact unpack, RNE pack) ----
__device__ __forceinline__ float bf_lo(unsigned u) { return __uint_as_float(u << 16); }
__device__ __forceinline__ float bf_hi(unsigned u) { return __uint_as_float(u & 0xffff0000u); }
__device__ __forceinline__ unsigned f2bf_bits(float f) {
  unsigned x = __float_as_uint(f);
  return (x + 0x7fffu + ((x >> 16) & 1u)) >> 16;   // round-nearest-even
}
__device__ __forceinline__ unsigned pack_bf16(float a, float b) {
  return f2bf_bits(a) | (f2bf_bits(b) << 16);
}

// ---------------- degree histogram / dinv ----------------
__global__ void k_hist(const int* __restrict__ dst, int* __restrict__ deg, int E) {
  int e = blockIdx.x * blockDim.x + threadIdx.x;
  if (e < E) atomicAdd(&deg[dst[e]], 1);
}

__global__ void k_dinv(const int* __restrict__ deg, float* __restrict__ dinv, int n) {
  int i = blockIdx.x * blockDim.x + threadIdx.x;
  if (i < n) dinv[i] = rsqrtf((float)(deg[i] + 1));  // +1 self-loop
}

// ---------------- exclusive scan (3-phase) ----------------
__global__ void k_scanA(const int* __restrict__ deg, int* __restrict__ row_ptr,
                        int* __restrict__ psum, int n) {
  __shared__ int s[256];
  int tid = threadIdx.x;
  int i = blockIdx.x * 256 + tid;
  int v = (i < n) ? deg[i] : 0;
  s[tid] = v;
  __syncthreads();
  for (int off = 1; off < 256; off <<= 1) {
    int t = (tid >= off) ? s[tid - off] : 0;
    __syncthreads();
    s[tid] += t;
    __syncthreads();
  }
  if (i < n) row_ptr[i] = s[tid] - v;
  if (tid == 255) psum[blockIdx.x] = s[255];
}

__global__ void k_scanB(int* psum, int nb) {
  __shared__ int s[512];
  int tid = threadIdx.x;
  int v = (tid < nb) ? psum[tid] : 0;
  s[tid] = v;
  __syncthreads();
  for (int off = 1; off < 512; off <<= 1) {
    int t = (tid >= off) ? s[tid - off] : 0;
    __syncthreads();
    s[tid] += t;
    __syncthreads();
  }
  if (tid < nb) psum[tid] = s[tid] - v;
}

__global__ void k_scanC(int* row_ptr, const int* __restrict__ psum, int n, int E) {
  int i = blockIdx.x * blockDim.x + threadIdx.x;
  if (i < n) row_ptr[i] += psum[i >> 8];
  if (i == 0) row_ptr[n] = E;
}

// ---------------- CSR scatter ----------------
__global__ void k_scatter(const int* __restrict__ src, const int* __restrict__ dst,
                          const int* __restrict__ row_ptr, int* __restrict__ fill,
                          int* __restrict__ col_src, int E) {
  int e = blockIdx.x * blockDim.x + threadIdx.x;
  if (e >= E) return;
  int d = dst[e];
  int pos = row_ptr[d] + atomicAdd(&fill[d], 1);
  col_src[pos] = src[e];
}

// ------- W1 cast: W1bf[col][k] = bf16(W1[k][col]), padded to 112 cols -------
__global__ void k_w1cast(const float* __restrict__ W1, unsigned short* __restrict__ W1bf) {
  int i = blockIdx.x * 256 + threadIdx.x;
  if (i >= NPAD * FDIM) return;
  int col = i / FDIM, k = i % FDIM;
  float v = (col < H1) ? W1[k * H1 + col] : 0.f;
  W1bf[i] = (unsigned short)f2bf_bits(v);
}

// ------ GEMM1 (MFMA, no LDS): t1p[r][c] = bf16( (x@W1)[r][c] * dinv[r] ) ----
// 4 waves/block, each wave owns 16 rows x 112 cols, K=256.
// ALL 16 A-loads hoisted (independent, in flight together); launch_bounds(256,3)
// caps occupancy at 12 waves/CU but gives ~170 VGPRs so nothing serializes on
// register reuse (R3: VGPR=56 -> zero MLP -> 87us latency-bound).
__global__ __launch_bounds__(256, 3)
void k_gemm1m(const float* __restrict__ x, const unsigned short* __restrict__ W1bf,
              const float* __restrict__ dinv, unsigned short* __restrict__ t1p, int n) {
  int tid = threadIdx.x;
  int lane = tid & 63, w = tid >> 6;
  int lr = lane & 15, lg = lane >> 4;
  int r0 = blockIdx.x * 64 + w * 16;
  int arow = r0 + lr;
  const float* xrow = x + (size_t)(arow < n ? arow : 0) * FDIM;

  // hoist ALL A loads: 16 independent float4 loads covering K=256
  float4 va[16];
#pragma unroll
  for (int s = 0; s < 8; ++s) {
    int kb = s * 32 + lg * 8;
    va[2 * s]     = *(const float4*)(xrow + kb);
    va[2 * s + 1] = *(const float4*)(xrow + kb + 4);
  }
  bf16x8 af[8];
#pragma unroll
  for (int s = 0; s < 8; ++s) {
    uint4 au;
    au.x = pack_bf16(va[2 * s].x, va[2 * s].y);
    au.y = pack_bf16(va[2 * s].z, va[2 * s].w);
    au.z = pack_bf16(va[2 * s + 1].x, va[2 * s + 1].y);
    au.w = pack_bf16(va[2 * s + 1].z, va[2 * s + 1].w);
    af[s] = *(bf16x8*)&au;
  }

  f32x4 acc[7];
#pragma unroll
  for (int nt = 0; nt < 7; nt++) acc[nt] = (f32x4){0.f, 0.f, 0.f, 0.f};

#pragma unroll
  for (int s = 0; s < 8; ++s) {
    int kb = s * 32 + lg * 8;
#pragma unroll
    for (int nt = 0; nt < 7; nt++) {
      int col = nt * 16 + lr;
      bf16x8 b = *(const bf16x8*)(W1bf + (size_t)col * FDIM + kb);
      acc[nt] = __builtin_amdgcn_mfma_f32_16x16x32_bf16(af[s], b, acc[nt], 0, 0, 0);
    }
  }

  // epilogue: D col = lane&15, row = (lane>>4)*4 + r
  float dv[4];
  int rbase = r0 + lg * 4;
#pragma unroll
  for (int r = 0; r < 4; r++) dv[r] = (rbase + r < n) ? dinv[rbase + r] : 0.f;
#pragma unroll
  for (int nt = 0; nt < 7; nt++) {
    int col = nt * 16 + lr;
    if (col < H1) {
#pragma unroll
      for (int r = 0; r < 4; r++) {
        int row = rbase + r;
        if (row < n)
          t1p[(size_t)row * H1 + col] = (unsigned short)f2bf_bits(acc[nt][r] * dv[r]);
      }
    }
  }
}

// ---- agg1: h[d] = bf16(relu(dinv[d]*(sum t1p[s] + t1p[d]) + b1)) -----------
// wave per node; lanes 0..49 each own 2 cols; edge loop unrolled x8 for MLP.
__global__ __launch_bounds__(256)
void k_agg1(const unsigned* __restrict__ t1p, const int* __restrict__ row_ptr,
            const int* __restrict__ col_src, const float* __restrict__ dinv,
            const float* __restrict__ b1, unsigned* __restrict__ h, int n) {
  int wid = (int)((blockIdx.x * (size_t)blockDim.x + threadIdx.x) >> 6);
  if (wid >= n) return;
  int lane = threadIdx.x & 63;
  if (lane >= 50) return;
  int beg = row_ptr[wid], end = row_ptr[wid + 1];
  float a0 = 0.f, a1 = 0.f;
  for (int e = beg; e < end; e += 8) {
    int last = end - 1;
    int i1 = e + 1 < end ? e + 1 : last;
    int i2 = e + 2 < end ? e + 2 : last;
    int i3 = e + 3 < end ? e + 3 : last;
    int i4 = e + 4 < end ? e + 4 : last;
    int i5 = e + 5 < end ? e + 5 : last;
    int i6 = e + 6 < end ? e + 6 : last;
    int i7 = e + 7 < end ? e + 7 : last;
    int s0 = col_src[e],  s1 = col_src[i1], s2 = col_src[i2], s3 = col_src[i3];
    int s4 = col_src[i4], s5 = col_src[i5], s6 = col_src[i6], s7 = col_src[i7];
    unsigned u0 = t1p[(size_t)s0 * 50 + lane];
    unsigned u1 = t1p[(size_t)s1 * 50 + lane];
    unsigned u2 = t1p[(size_t)s2 * 50 + lane];
    unsigned u3 = t1p[(size_t)s3 * 50 + lane];
    unsigned u4 = t1p[(size_t)s4 * 50 + lane];
    unsigned u5 = t1p[(size_t)s5 * 50 + lane];
    unsigned u6 = t1p[(size_t)s6 * 50 + lane];
    unsigned u7 = t1p[(size_t)s7 * 50 + lane];
    a0 += bf_lo(u0); a1 += bf_hi(u0);
    if (e + 1 < end) { a0 += bf_lo(u1); a1 += bf_hi(u1); }
    if (e + 2 < end) { a0 += bf_lo(u2); a1 += bf_hi(u2); }
    if (e + 3 < end) { a0 += bf_lo(u3); a1 += bf_hi(u3); }
    if (e + 4 < end) { a0 += bf_lo(u4); a1 += bf_hi(u4); }
    if (e + 5 < end) { a0 += bf_lo(u5); a1 += bf_hi(u5); }
    if (e + 6 < end) { a0 += bf_lo(u6); a1 += bf_hi(u6); }
    if (e + 7 < end) { a0 += bf_lo(u7); a1 += bf_hi(u7); }
  }
  unsigned su = t1p[(size_t)wid * 50 + lane];
  a0 += bf_lo(su);
  a1 += bf_hi(su);
  float dv = dinv[wid];
  float v0 = fmaxf(dv * a0 + b1[2 * lane], 0.f);
  float v1 = fmaxf(dv * a1 + b1[2 * lane + 1], 0.f);
  h[(size_t)wid * 50 + lane] = pack_bf16(v0, v1);
}

// ------ GEMM2: t2p = bf16( (h @ W2) * dinv )  (N x 100 x 16) ----------------
__global__ __launch_bounds__(256)
void k_gemm2(const unsigned* __restrict__ h, const float* __restrict__ W2,
             const float* __restrict__ dinv, unsigned* __restrict__ t2p, int n) {
  __shared__ alignas(16) float w2s[100][16];
  __shared__ float hs[64][101];
  int tid = threadIdx.x;
  int r0 = blockIdx.x * 64;
  for (int idx = tid; idx < H1 * H2; idx += 256) w2s[idx / 16][idx % 16] = W2[idx];
  for (int idx = tid; idx < 64 * 50; idx += 256) {
    int row = idx / 50, u = idx % 50;
    int gr = r0 + row;
    unsigned v = 0;
    if (gr < n) v = h[(size_t)gr * 50 + u];
    hs[row][2 * u + 0] = bf_lo(v);
    hs[row][2 * u + 1] = bf_hi(v);
  }
  __syncthreads();
  int r = tid & 63, cg = tid >> 6;
  float ax = 0.f, ay = 0.f, az = 0.f, aw = 0.f;
#pragma unroll 4
  for (int k = 0; k < H1; ++k) {
    float a = hs[r][k];
    float4 w = *(const float4*)&w2s[k][cg * 4];
    ax += a * w.x; ay += a * w.y; az += a * w.z; aw += a * w.w;
  }
  int gr = r0 + r;
  if (gr < n) {
    float dv = dinv[gr];
    unsigned u0 = pack_bf16(ax * dv, ay * dv);
    unsigned u1 = pack_bf16(az * dv, aw * dv);
    *(uint2*)(t2p + (size_t)gr * 8 + cg * 2) = make_uint2(u0, u1);
  }
}

// ------- agg2 + bias + relu + row-normalize: emb (N x 16, f32) --------------
__global__ __launch_bounds__(256)
void k_agg2(const unsigned* __restrict__ t2p, const int* __restrict__ row_ptr,
            const int* __restrict__ col_src, const float* __restrict__ dinv,
            const float* __restrict__ b2, float* __restrict__ emb, int n) {
  int wid = (int)((blockIdx.x * (size_t)blockDim.x + threadIdx.x) >> 6);
  if (wid >= n) return;
  int lane = threadIdx.x & 63;
  int es = lane >> 3, c = lane & 7;
  int beg = row_ptr[wid], end = row_ptr[wid + 1];
  float a0 = 0.f, a1 = 0.f;
  for (int e = beg + es; e < end; e += 8) {
    int s = col_src[e];
    unsigned u = t2p[(size_t)s * 8 + c];
    a0 += bf_lo(u);
    a1 += bf_hi(u);
  }
  a0 += __shfl_xor(a0, 8, 64);  a1 += __shfl_xor(a1, 8, 64);
  a0 += __shfl_xor(a0, 16, 64); a1 += __shfl_xor(a1, 16, 64);
  a0 += __shfl_xor(a0, 32, 64); a1 += __shfl_xor(a1, 32, 64);
  unsigned su = t2p[(size_t)wid * 8 + c];
  a0 += bf_lo(su);
  a1 += bf_hi(su);
  float dv = dinv[wid];
  float v0 = fmaxf(dv * a0 + b2[2 * c + 0], 0.f);
  float v1 = fmaxf(dv * a1 + b2[2 * c + 1], 0.f);
  float n2 = v0 * v0 + v1 * v1;
  n2 += __shfl_xor(n2, 1, 64);
  n2 += __shfl_xor(n2, 2, 64);
  n2 += __shfl_xor(n2, 4, 64);
  float scale = 1.f / fmaxf(sqrtf(n2), 1.f);
  if (es == 0) {
    *(float2*)(emb + (size_t)wid * H2 + 2 * c) = make_float2(v0 * scale, v1 * scale);
  }
}

// ---------------- edge scorer ------------------------------------------------
__global__ __launch_bounds__(256)
void k_score(const float* __restrict__ emb, const int* __restrict__ te,
             const float* __restrict__ PI, const float* __restrict__ l1W,
             const float* __restrict__ l1b, const float* __restrict__ lW,
             const float* __restrict__ lb, float* __restrict__ out, int ned) {
  __shared__ alignas(16) float wT[25][44];
  __shared__ float sb1[25], sw2[25];
  for (int idx = threadIdx.x; idx < 41 * 25; idx += blockDim.x) {
    int i = idx / 25, j = idx % 25;
    wT[j][i] = l1W[idx];
  }
  for (int idx = threadIdx.x; idx < 25; idx += blockDim.x) {
    sb1[idx] = l1b[idx];
    sw2[idx] = lW[idx];
  }
  __syncthreads();
  int e = blockIdx.x * blockDim.x + threadIdx.x;
  if (e >= ned) return;
  int u = te[2 * e], v = te[2 * e + 1];
  float f[41];
  const float4* eu = (const float4*)(emb + (size_t)u * H2);
  const float4* ev = (const float4*)(emb + (size_t)v * H2);
#pragma unroll
  for (int q = 0; q < 4; q++) {
    float4 a = eu[q], b = ev[q];
    float dx = a.x - b.x, dy = a.y - b.y, dz = a.z - b.z, dw = a.w - b.w;
    f[q * 4 + 0] = dx * dx; f[q * 4 + 1] = dy * dy;
    f[q * 4 + 2] = dz * dz; f[q * 4 + 3] = dw * dw;
  }
  const float* pi = PI + (size_t)e * 25;
#pragma unroll
  for (int i = 0; i < 25; i++) f[16 + i] = pi[i];
  float acc2 = lb[0];
  for (int j = 0; j < 25; j++) {
    float a = sb1[j];
#pragma unroll
    for (int i = 0; i < 41; i++) a += f[i] * wT[j][i];
    a = (a > 0.f) ? a : 0.2f * a;
    acc2 += a * sw2[j];
  }
  float s = fminf(fabsf(acc2), 40.f);
  float z = 2.f - s;
  out[e] = 1.f / (1.f + __expf(-z));
}

// ---------------- launch -----------------------------------------------------
extern "C" void kernel_launch(void* const* d_in, const int* in_sizes, int n_in,
                              void* d_out, int out_size, void* d_ws, size_t ws_size,
                              hipStream_t stream) {
  const float* x   = (const float*)d_in[0];
  const int*   ei  = (const int*)d_in[1];
  const int*   te  = (const int*)d_in[2];
  const float* PI  = (const float*)d_in[3];
  const float* W1  = (const float*)d_in[4];
  const float* b1  = (const float*)d_in[5];
  const float* W2  = (const float*)d_in[6];
  const float* b2  = (const float*)d_in[7];
  const float* l1W = (const float*)d_in[8];
  const float* l1b = (const float*)d_in[9];
  const float* lW  = (const float*)d_in[10];
  const float* lb  = (const float*)d_in[11];
  float* out = (float*)d_out;

  int h1 = in_sizes[5];            // 100
  int F  = in_sizes[4] / h1;       // 256
  int N  = in_sizes[0] / F;        // 100000
  int E  = in_sizes[1] / 2;        // 1600000
  int ED = in_sizes[2] / 2;        // 1000000

  const int* src  = ei;
  const int* dstp = ei + E;

  size_t off = 0;
  auto alloc = [&](size_t bytes) -> void* {
    void* p = (char*)d_ws + off;
    off += (bytes + 255) & ~(size_t)255;
    return p;
  };
  int*            deg     = (int*)alloc((size_t)N * 4);
  float*          dinv    = (float*)alloc((size_t)N * 4);
  int*            row_ptr = (int*)alloc((size_t)(N + 1) * 4);
  int*            fill    = (int*)alloc((size_t)N * 4);
  int*            psum    = (int*)alloc(512 * 4);
  int*            col_src = (int*)alloc((size_t)E * 4);
  unsigned short* W1bf    = (unsigned short*)alloc((size_t)NPAD * FDIM * 2);
  unsigned*       t1p     = (unsigned*)alloc((size_t)N * 50 * 4);  // bf16 x2 packed
  unsigned*       h       = (unsigned*)alloc((size_t)N * 50 * 4);
  unsigned*       t2p     = (unsigned*)alloc((size_t)N * 8 * 4);
  float*          emb     = (float*)alloc((size_t)N * H2 * 4);

  int nb = (N + 255) / 256;

  hipMemsetAsync(deg, 0, (size_t)N * 4, stream);
  k_hist<<<(E + 255) / 256, 256, 0, stream>>>(dstp, deg, E);
  k_dinv<<<(N + 255) / 256, 256, 0, stream>>>(deg, dinv, N);
  k_scanA<<<nb, 256, 0, stream>>>(deg, row_ptr, psum, N);
  k_scanB<<<1, 512, 0, stream>>>(psum, nb);
  k_scanC<<<nb, 256, 0, stream>>>(row_ptr, psum, N, E);
  hipMemsetAsync(fill, 0, (size_t)N * 4, stream);
  k_scatter<<<(E + 255) / 256, 256, 0, stream>>>(src, dstp, row_ptr, fill, col_src, E);
  k_w1cast<<<(NPAD * FDIM + 255) / 256, 256, 0, stream>>>(W1, W1bf);
  k_gemm1m<<<(N + 63) / 64, 256, 0, stream>>>(x, W1bf, dinv, (unsigned short*)t1p, N);
  k_agg1<<<(int)(((size_t)N * 64 + 255) / 256), 256, 0, stream>>>(t1p, row_ptr, col_src, dinv, b1, h, N);
  k_gemm2<<<(N + 63) / 64, 256, 0, stream>>>(h, W2, dinv, t2p, N);
  k_agg2<<<(int)(((size_t)N * 64 + 255) / 256), 256, 0, stream>>>(t2p, row_ptr, col_src, dinv, b2, emb, N);
  k_score<<<(ED + 255) / 256, 256, 0, stream>>>(emb, te, PI, l1W, l1b, lW, lb, out, ED);
}

// Round 6
// 339.947 us; speedup vs baseline: 1.2219x; 1.2219x over previous
//
#include <hip/hip_runtime.h>
#include <hip/hip_bf16.h>
#include <math.h>

#define H1 100
#define H2 16
#define FDIM 256
#define NPAD 112   // H1 padded to 7*16
#define BINCH 4096 // edges per binning workgroup

typedef __attribute__((ext_vector_type(8))) short bf16x8;
typedef __attribute__((ext_vector_type(4))) float f32x4;

// ---- bf16 pack/unpack helpers (bit-exact unpack, RNE pack) ----
__device__ __forceinline__ float bf_lo(unsigned u) { return __uint_as_float(u << 16); }
__device__ __forceinline__ float bf_hi(unsigned u) { return __uint_as_float(u & 0xffff0000u); }
__device__ __forceinline__ unsigned f2bf_bits(float f) {
  unsigned x = __float_as_uint(f);
  return (x + 0x7fffu + ((x >> 16) & 1u)) >> 16;   // round-nearest-even
}
__device__ __forceinline__ unsigned pack_bf16(float a, float b) {
  return f2bf_bits(a) | (f2bf_bits(b) << 16);
}

// ============ CSR build via bucket binning (replaces hist+scatter) ==========
// bucket b = dst >> shift covers nodes [b<<shift, (b+1)<<shift).

// pass 1: count edges per bucket (LDS hist -> 1 global atomic per bucket/wg)
__global__ __launch_bounds__(256)
void k_bincnt(const int* __restrict__ dst, int* __restrict__ bucket_cnt,
              int E, int shift) {
  __shared__ int lcnt[512];
  int t = threadIdx.x;
  for (int i = t; i < 512; i += 256) lcnt[i] = 0;
  __syncthreads();
  int base = blockIdx.x * BINCH;
#pragma unroll
  for (int i = 0; i < 16; i++) {
    int e = base + t + i * 256;
    if (e < E) atomicAdd(&lcnt[dst[e] >> shift], 1);
  }
  __syncthreads();
  for (int b = t; b < 512; b += 256) {
    int c = lcnt[b];
    if (c > 0) atomicAdd(&bucket_cnt[b], c);
  }
}

// pass 2: exclusive scan of bucket counts (<=512 buckets)
__global__ void k_bscan(const int* __restrict__ bucket_cnt, int* __restrict__ bucket_base,
                        int* __restrict__ bucket_fill, int nbuc, int E) {
  __shared__ int s[512];
  int tid = threadIdx.x;
  int v = (tid < nbuc) ? bucket_cnt[tid] : 0;
  s[tid] = v;
  __syncthreads();
  for (int off = 1; off < 512; off <<= 1) {
    int tt = (tid >= off) ? s[tid - off] : 0;
    __syncthreads();
    s[tid] += tt;
    __syncthreads();
  }
  if (tid < nbuc) { int ex = s[tid] - v; bucket_base[tid] = ex; bucket_fill[tid] = ex; }
  if (tid == 0) bucket_base[nbuc] = E;
}

// pass 3: write (src,dst) pairs binned by bucket (sequential-ish per bucket)
__global__ __launch_bounds__(256)
void k_binwrite(const int* __restrict__ src, const int* __restrict__ dst,
                int* __restrict__ bucket_fill, int* __restrict__ tsrc,
                int* __restrict__ tdst, int E, int shift) {
  __shared__ int lcnt[512];
  __shared__ int loff[512];
  int t = threadIdx.x;
  for (int i = t; i < 512; i += 256) lcnt[i] = 0;
  __syncthreads();
  int base = blockIdx.x * BINCH;
  int d[16], s_[16];
#pragma unroll
  for (int i = 0; i < 16; i++) {
    int e = base + t + i * 256;
    if (e < E) {
      d[i] = dst[e]; s_[i] = src[e];
      atomicAdd(&lcnt[d[i] >> shift], 1);
    } else d[i] = -1;
  }
  __syncthreads();
  for (int b = t; b < 512; b += 256) {
    int c = lcnt[b];
    loff[b] = (c > 0) ? atomicAdd(&bucket_fill[b], c) : 0;
  }
  __syncthreads();
#pragma unroll
  for (int i = 0; i < 16; i++) {
    if (d[i] >= 0) {
      int p = atomicAdd(&loff[d[i] >> shift], 1);
      tdst[p] = d[i];
      tsrc[p] = s_[i];
    }
  }
}

// pass 4: per-bucket degree histogram in LDS (+fused dinv); coalesced writes
__global__ __launch_bounds__(256)
void k_deg2(const int* __restrict__ tdst, const int* __restrict__ bucket_base,
            int* __restrict__ deg, float* __restrict__ dinv, int N, int shift) {
  __shared__ int lcnt[1024];
  int b = blockIdx.x, t = threadIdx.x;
  int bs = 1 << shift, mask = bs - 1;
  for (int i = t; i < bs; i += 256) lcnt[i] = 0;
  __syncthreads();
  int r0 = bucket_base[b], r1 = bucket_base[b + 1];
  for (int e = r0 + t; e < r1; e += 256) atomicAdd(&lcnt[tdst[e] & mask], 1);
  __syncthreads();
  for (int i = t; i < bs; i += 256) {
    int node = (b << shift) + i;
    if (node < N) {
      deg[node] = lcnt[i];
      dinv[node] = rsqrtf((float)(lcnt[i] + 1));  // +1 self-loop
    }
  }
}

// pass 5: exact CSR placement with LDS fill counters; writes stay in-bucket
__global__ __launch_bounds__(256)
void k_csr2(const int* __restrict__ tsrc, const int* __restrict__ tdst,
            const int* __restrict__ bucket_base, const int* __restrict__ row_ptr,
            int* __restrict__ col_src, int N, int shift) {
  __shared__ int lrp[1024];
  __shared__ int lfill[1024];
  int b = blockIdx.x, t = threadIdx.x;
  int bs = 1 << shift, mask = bs - 1;
  for (int i = t; i < bs; i += 256) {
    int node = (b << shift) + i;
    lrp[i] = row_ptr[node < N ? node : N];
    lfill[i] = 0;
  }
  __syncthreads();
  int r0 = bucket_base[b], r1 = bucket_base[b + 1];
  for (int e = r0 + t; e < r1; e += 256) {
    int dl = tdst[e] & mask;
    int p = lrp[dl] + atomicAdd(&lfill[dl], 1);
    col_src[p] = tsrc[e];
  }
}

// ---------------- exclusive scan over node degrees (3-phase) ----------------
__global__ void k_scanA(const int* __restrict__ deg, int* __restrict__ row_ptr,
                        int* __restrict__ psum, int n) {
  __shared__ int s[256];
  int tid = threadIdx.x;
  int i = blockIdx.x * 256 + tid;
  int v = (i < n) ? deg[i] : 0;
  s[tid] = v;
  __syncthreads();
  for (int off = 1; off < 256; off <<= 1) {
    int t = (tid >= off) ? s[tid - off] : 0;
    __syncthreads();
    s[tid] += t;
    __syncthreads();
  }
  if (i < n) row_ptr[i] = s[tid] - v;
  if (tid == 255) psum[blockIdx.x] = s[255];
}

__global__ void k_scanB(int* psum, int nb) {
  __shared__ int s[512];
  int tid = threadIdx.x;
  int v = (tid < nb) ? psum[tid] : 0;
  s[tid] = v;
  __syncthreads();
  for (int off = 1; off < 512; off <<= 1) {
    int t = (tid >= off) ? s[tid - off] : 0;
    __syncthreads();
    s[tid] += t;
    __syncthreads();
  }
  if (tid < nb) psum[tid] = s[tid] - v;
}

__global__ void k_scanC(int* row_ptr, const int* __restrict__ psum, int n, int E) {
  int i = blockIdx.x * blockDim.x + threadIdx.x;
  if (i < n) row_ptr[i] += psum[i >> 8];
  if (i == 0) row_ptr[n] = E;
}

// ------- W1 cast: W1bf[col][k] = bf16(W1[k][col]), padded to 112 cols -------
__global__ void k_w1cast(const float* __restrict__ W1, unsigned short* __restrict__ W1bf) {
  int i = blockIdx.x * 256 + threadIdx.x;
  if (i >= NPAD * FDIM) return;
  int col = i / FDIM, k = i % FDIM;
  float v = (col < H1) ? W1[k * H1 + col] : 0.f;
  W1bf[i] = (unsigned short)f2bf_bits(v);
}

// ------ GEMM1 (MFMA, no LDS): t1p[r][c] = bf16( (x@W1)[r][c] * dinv[r] ) ----
// launch_bounds(256,3): VGPR headroom so all 16 A-loads stay in flight (R3/R4:
// VGPR=56 cap -> zero MLP -> latency-bound).
__global__ __launch_bounds__(256, 3)
void k_gemm1m(const float* __restrict__ x, const unsigned short* __restrict__ W1bf,
              const float* __restrict__ dinv, unsigned short* __restrict__ t1p, int n) {
  int tid = threadIdx.x;
  int lane = tid & 63, w = tid >> 6;
  int lr = lane & 15, lg = lane >> 4;
  int r0 = blockIdx.x * 64 + w * 16;
  int arow = r0 + lr;
  const float* xrow = x + (size_t)(arow < n ? arow : 0) * FDIM;

  float4 va[16];
#pragma unroll
  for (int s = 0; s < 8; ++s) {
    int kb = s * 32 + lg * 8;
    va[2 * s]     = *(const float4*)(xrow + kb);
    va[2 * s + 1] = *(const float4*)(xrow + kb + 4);
  }
  bf16x8 af[8];
#pragma unroll
  for (int s = 0; s < 8; ++s) {
    uint4 au;
    au.x = pack_bf16(va[2 * s].x, va[2 * s].y);
    au.y = pack_bf16(va[2 * s].z, va[2 * s].w);
    au.z = pack_bf16(va[2 * s + 1].x, va[2 * s + 1].y);
    au.w = pack_bf16(va[2 * s + 1].z, va[2 * s + 1].w);
    af[s] = *(bf16x8*)&au;
  }

  f32x4 acc[7];
#pragma unroll
  for (int nt = 0; nt < 7; nt++) acc[nt] = (f32x4){0.f, 0.f, 0.f, 0.f};

#pragma unroll
  for (int s = 0; s < 8; ++s) {
    int kb = s * 32 + lg * 8;
#pragma unroll
    for (int nt = 0; nt < 7; nt++) {
      int col = nt * 16 + lr;
      bf16x8 b = *(const bf16x8*)(W1bf + (size_t)col * FDIM + kb);
      acc[nt] = __builtin_amdgcn_mfma_f32_16x16x32_bf16(af[s], b, acc[nt], 0, 0, 0);
    }
  }

  float dv[4];
  int rbase = r0 + lg * 4;
#pragma unroll
  for (int r = 0; r < 4; r++) dv[r] = (rbase + r < n) ? dinv[rbase + r] : 0.f;
#pragma unroll
  for (int nt = 0; nt < 7; nt++) {
    int col = nt * 16 + lr;
    if (col < H1) {
#pragma unroll
      for (int r = 0; r < 4; r++) {
        int row = rbase + r;
        if (row < n)
          t1p[(size_t)row * H1 + col] = (unsigned short)f2bf_bits(acc[nt][r] * dv[r]);
      }
    }
  }
}

// ---- agg1: h[d] = bf16(relu(dinv[d]*(sum t1p[s] + t1p[d]) + b1)) -----------
__global__ __launch_bounds__(256)
void k_agg1(const unsigned* __restrict__ t1p, const int* __restrict__ row_ptr,
            const int* __restrict__ col_src, const float* __restrict__ dinv,
            const float* __restrict__ b1, unsigned* __restrict__ h, int n) {
  int wid = (int)((blockIdx.x * (size_t)blockDim.x + threadIdx.x) >> 6);
  if (wid >= n) return;
  int lane = threadIdx.x & 63;
  if (lane >= 50) return;
  int beg = row_ptr[wid], end = row_ptr[wid + 1];
  float a0 = 0.f, a1 = 0.f;
  for (int e = beg; e < end; e += 8) {
    int last = end - 1;
    int i1 = e + 1 < end ? e + 1 : last;
    int i2 = e + 2 < end ? e + 2 : last;
    int i3 = e + 3 < end ? e + 3 : last;
    int i4 = e + 4 < end ? e + 4 : last;
    int i5 = e + 5 < end ? e + 5 : last;
    int i6 = e + 6 < end ? e + 6 : last;
    int i7 = e + 7 < end ? e + 7 : last;
    int s0 = col_src[e],  s1 = col_src[i1], s2 = col_src[i2], s3 = col_src[i3];
    int s4 = col_src[i4], s5 = col_src[i5], s6 = col_src[i6], s7 = col_src[i7];
    unsigned u0 = t1p[(size_t)s0 * 50 + lane];
    unsigned u1 = t1p[(size_t)s1 * 50 + lane];
    unsigned u2 = t1p[(size_t)s2 * 50 + lane];
    unsigned u3 = t1p[(size_t)s3 * 50 + lane];
    unsigned u4 = t1p[(size_t)s4 * 50 + lane];
    unsigned u5 = t1p[(size_t)s5 * 50 + lane];
    unsigned u6 = t1p[(size_t)s6 * 50 + lane];
    unsigned u7 = t1p[(size_t)s7 * 50 + lane];
    a0 += bf_lo(u0); a1 += bf_hi(u0);
    if (e + 1 < end) { a0 += bf_lo(u1); a1 += bf_hi(u1); }
    if (e + 2 < end) { a0 += bf_lo(u2); a1 += bf_hi(u2); }
    if (e + 3 < end) { a0 += bf_lo(u3); a1 += bf_hi(u3); }
    if (e + 4 < end) { a0 += bf_lo(u4); a1 += bf_hi(u4); }
    if (e + 5 < end) { a0 += bf_lo(u5); a1 += bf_hi(u5); }
    if (e + 6 < end) { a0 += bf_lo(u6); a1 += bf_hi(u6); }
    if (e + 7 < end) { a0 += bf_lo(u7); a1 += bf_hi(u7); }
  }
  unsigned su = t1p[(size_t)wid * 50 + lane];
  a0 += bf_lo(su);
  a1 += bf_hi(su);
  float dv = dinv[wid];
  float v0 = fmaxf(dv * a0 + b1[2 * lane], 0.f);
  float v1 = fmaxf(dv * a1 + b1[2 * lane + 1], 0.f);
  h[(size_t)wid * 50 + lane] = pack_bf16(v0, v1);
}

// ------ GEMM2: t2p = bf16( (h @ W2) * dinv )  (N x 100 x 16) ----------------
__global__ __launch_bounds__(256)
void k_gemm2(const unsigned* __restrict__ h, const float* __restrict__ W2,
             const float* __restrict__ dinv, unsigned* __restrict__ t2p, int n) {
  __shared__ alignas(16) float w2s[100][16];
  __shared__ float hs[64][101];
  int tid = threadIdx.x;
  int r0 = blockIdx.x * 64;
  for (int idx = tid; idx < H1 * H2; idx += 256) w2s[idx / 16][idx % 16] = W2[idx];
  for (int idx = tid; idx < 64 * 50; idx += 256) {
    int row = idx / 50, u = idx % 50;
    int gr = r0 + row;
    unsigned v = 0;
    if (gr < n) v = h[(size_t)gr * 50 + u];
    hs[row][2 * u + 0] = bf_lo(v);
    hs[row][2 * u + 1] = bf_hi(v);
  }
  __syncthreads();
  int r = tid & 63, cg = tid >> 6;
  float ax = 0.f, ay = 0.f, az = 0.f, aw = 0.f;
#pragma unroll 4
  for (int k = 0; k < H1; ++k) {
    float a = hs[r][k];
    float4 w = *(const float4*)&w2s[k][cg * 4];
    ax += a * w.x; ay += a * w.y; az += a * w.z; aw += a * w.w;
  }
  int gr = r0 + r;
  if (gr < n) {
    float dv = dinv[gr];
    unsigned u0 = pack_bf16(ax * dv, ay * dv);
    unsigned u1 = pack_bf16(az * dv, aw * dv);
    *(uint2*)(t2p + (size_t)gr * 8 + cg * 2) = make_uint2(u0, u1);
  }
}

// ------- agg2 + bias + relu + row-normalize: emb (N x 16, f32) --------------
__global__ __launch_bounds__(256)
void k_agg2(const unsigned* __restrict__ t2p, const int* __restrict__ row_ptr,
            const int* __restrict__ col_src, const float* __restrict__ dinv,
            const float* __restrict__ b2, float* __restrict__ emb, int n) {
  int wid = (int)((blockIdx.x * (size_t)blockDim.x + threadIdx.x) >> 6);
  if (wid >= n) return;
  int lane = threadIdx.x & 63;
  int es = lane >> 3, c = lane & 7;
  int beg = row_ptr[wid], end = row_ptr[wid + 1];
  float a0 = 0.f, a1 = 0.f;
  for (int e = beg + es; e < end; e += 8) {
    int s = col_src[e];
    unsigned u = t2p[(size_t)s * 8 + c];
    a0 += bf_lo(u);
    a1 += bf_hi(u);
  }
  a0 += __shfl_xor(a0, 8, 64);  a1 += __shfl_xor(a1, 8, 64);
  a0 += __shfl_xor(a0, 16, 64); a1 += __shfl_xor(a1, 16, 64);
  a0 += __shfl_xor(a0, 32, 64); a1 += __shfl_xor(a1, 32, 64);
  unsigned su = t2p[(size_t)wid * 8 + c];
  a0 += bf_lo(su);
  a1 += bf_hi(su);
  float dv = dinv[wid];
  float v0 = fmaxf(dv * a0 + b2[2 * c + 0], 0.f);
  float v1 = fmaxf(dv * a1 + b2[2 * c + 1], 0.f);
  float n2 = v0 * v0 + v1 * v1;
  n2 += __shfl_xor(n2, 1, 64);
  n2 += __shfl_xor(n2, 2, 64);
  n2 += __shfl_xor(n2, 4, 64);
  float scale = 1.f / fmaxf(sqrtf(n2), 1.f);
  if (es == 0) {
    *(float2*)(emb + (size_t)wid * H2 + 2 * c) = make_float2(v0 * scale, v1 * scale);
  }
}

// ---------------- edge scorer ------------------------------------------------
__global__ __launch_bounds__(256)
void k_score(const float* __restrict__ emb, const int* __restrict__ te,
             const float* __restrict__ PI, const float* __restrict__ l1W,
             const float* __restrict__ l1b, const float* __restrict__ lW,
             const float* __restrict__ lb, float* __restrict__ out, int ned) {
  __shared__ alignas(16) float wT[25][44];
  __shared__ float sb1[25], sw2[25];
  for (int idx = threadIdx.x; idx < 41 * 25; idx += blockDim.x) {
    int i = idx / 25, j = idx % 25;
    wT[j][i] = l1W[idx];
  }
  for (int idx = threadIdx.x; idx < 25; idx += blockDim.x) {
    sb1[idx] = l1b[idx];
    sw2[idx] = lW[idx];
  }
  __syncthreads();
  int e = blockIdx.x * blockDim.x + threadIdx.x;
  if (e >= ned) return;
  int u = te[2 * e], v = te[2 * e + 1];
  float f[41];
  const float4* eu = (const float4*)(emb + (size_t)u * H2);
  const float4* ev = (const float4*)(emb + (size_t)v * H2);
#pragma unroll
  for (int q = 0; q < 4; q++) {
    float4 a = eu[q], b = ev[q];
    float dx = a.x - b.x, dy = a.y - b.y, dz = a.z - b.z, dw = a.w - b.w;
    f[q * 4 + 0] = dx * dx; f[q * 4 + 1] = dy * dy;
    f[q * 4 + 2] = dz * dz; f[q * 4 + 3] = dw * dw;
  }
  const float* pi = PI + (size_t)e * 25;
#pragma unroll
  for (int i = 0; i < 25; i++) f[16 + i] = pi[i];
  float acc2 = lb[0];
  for (int j = 0; j < 25; j++) {
    float a = sb1[j];
#pragma unroll
    for (int i = 0; i < 41; i++) a += f[i] * wT[j][i];
    a = (a > 0.f) ? a : 0.2f * a;
    acc2 += a * sw2[j];
  }
  float s = fminf(fabsf(acc2), 40.f);
  float z = 2.f - s;
  out[e] = 1.f / (1.f + __expf(-z));
}

// ---------------- launch -----------------------------------------------------
extern "C" void kernel_launch(void* const* d_in, const int* in_sizes, int n_in,
                              void* d_out, int out_size, void* d_ws, size_t ws_size,
                              hipStream_t stream) {
  const float* x   = (const float*)d_in[0];
  const int*   ei  = (const int*)d_in[1];
  const int*   te  = (const int*)d_in[2];
  const float* PI  = (const float*)d_in[3];
  const float* W1  = (const float*)d_in[4];
  const float* b1  = (const float*)d_in[5];
  const float* W2  = (const float*)d_in[6];
  const float* b2  = (const float*)d_in[7];
  const float* l1W = (const float*)d_in[8];
  const float* l1b = (const float*)d_in[9];
  const float* lW  = (const float*)d_in[10];
  const float* lb  = (const float*)d_in[11];
  float* out = (float*)d_out;

  int h1 = in_sizes[5];            // 100
  int F  = in_sizes[4] / h1;       // 256
  int N  = in_sizes[0] / F;        // 100000
  int E  = in_sizes[1] / 2;        // 1600000
  int ED = in_sizes[2] / 2;        // 1000000

  const int* src  = ei;
  const int* dstp = ei + E;

  // bucket shift: nbuc <= 512 and bucket size <= 1024
  int shift = 8;
  while ((((size_t)N + ((size_t)1 << shift) - 1) >> shift) > 512) shift++;
  int nbuc = (N + (1 << shift) - 1) >> shift;

  size_t off = 0;
  auto alloc = [&](size_t bytes) -> void* {
    void* p = (char*)d_ws + off;
    off += (bytes + 255) & ~(size_t)255;
    return p;
  };
  int*            deg      = (int*)alloc((size_t)N * 4);
  float*          dinv     = (float*)alloc((size_t)N * 4);
  int*            row_ptr  = (int*)alloc((size_t)(N + 1) * 4);
  int*            psum     = (int*)alloc(512 * 4);
  int*            bcnt     = (int*)alloc(512 * 4);
  int*            bbase    = (int*)alloc(520 * 4);
  int*            bfill    = (int*)alloc(512 * 4);
  int*            col_src  = (int*)alloc((size_t)E * 4);
  unsigned short* W1bf     = (unsigned short*)alloc((size_t)NPAD * FDIM * 2);
  unsigned*       t1p      = (unsigned*)alloc((size_t)N * 50 * 4);  // bf16 x2 packed
  unsigned*       h        = (unsigned*)alloc((size_t)N * 50 * 4);
  unsigned*       t2p      = (unsigned*)alloc((size_t)N * 8 * 4);
  float*          emb      = (float*)alloc((size_t)N * H2 * 4);

  // temp binned edge arrays alias h (dead until agg1; 2*E*4 = 12.8MB <= 20MB)
  int* tdst = (int*)h;
  int* tsrc = (int*)h + E;

  int nb = (N + 255) / 256;
  int nwb = (E + BINCH - 1) / BINCH;

  hipMemsetAsync(bcnt, 0, 512 * 4, stream);
  k_bincnt<<<nwb, 256, 0, stream>>>(dstp, bcnt, E, shift);
  k_bscan<<<1, 512, 0, stream>>>(bcnt, bbase, bfill, nbuc, E);
  k_binwrite<<<nwb, 256, 0, stream>>>(src, dstp, bfill, tsrc, tdst, E, shift);
  k_deg2<<<nbuc, 256, 0, stream>>>(tdst, bbase, deg, dinv, N, shift);
  k_scanA<<<nb, 256, 0, stream>>>(deg, row_ptr, psum, N);
  k_scanB<<<1, 512, 0, stream>>>(psum, nb);
  k_scanC<<<nb, 256, 0, stream>>>(row_ptr, psum, N, E);
  k_csr2<<<nbuc, 256, 0, stream>>>(tsrc, tdst, bbase, row_ptr, col_src, N, shift);
  k_w1cast<<<(NPAD * FDIM + 255) / 256, 256, 0, stream>>>(W1, W1bf);
  k_gemm1m<<<(N + 63) / 64, 256, 0, stream>>>(x, W1bf, dinv, (unsigned short*)t1p, N);
  k_agg1<<<(int)(((size_t)N * 64 + 255) / 256), 256, 0, stream>>>(t1p, row_ptr, col_src, dinv, b1, h, N);
  k_gemm2<<<(N + 63) / 64, 256, 0, stream>>>(h, W2, dinv, t2p, N);
  k_agg2<<<(int)(((size_t)N * 64 + 255) / 256), 256, 0, stream>>>(t2p, row_ptr, col_src, dinv, b2, emb, N);
  k_score<<<(ED + 255) / 256, 256, 0, stream>>>(emb, te, PI, l1W, l1b, lW, lb, out, ED);
}

// Round 7
// 316.987 us; speedup vs baseline: 1.3105x; 1.0724x over previous
//
#include <hip/hip_runtime.h>
#include <hip/hip_bf16.h>
#include <math.h>

#define H1 100
#define H2 16
#define FDIM 256
#define NPAD 112   // H1 padded to 7*16
#define BINCH 4096 // edges per binning workgroup

typedef __attribute__((ext_vector_type(8))) short bf16x8;
typedef __attribute__((ext_vector_type(4))) float f32x4;
typedef float f32x4a __attribute__((ext_vector_type(4), aligned(4)));  // 4B-aligned vec load

// ---- bf16 pack/unpack helpers (bit-exact unpack, RNE pack) ----
__device__ __forceinline__ float bf_lo(unsigned u) { return __uint_as_float(u << 16); }
__device__ __forceinline__ float bf_hi(unsigned u) { return __uint_as_float(u & 0xffff0000u); }
__device__ __forceinline__ unsigned f2bf_bits(float f) {
  unsigned x = __float_as_uint(f);
  return (x + 0x7fffu + ((x >> 16) & 1u)) >> 16;   // round-nearest-even
}
__device__ __forceinline__ unsigned pack_bf16(float a, float b) {
  return f2bf_bits(a) | (f2bf_bits(b) << 16);
}

// ============ CSR build via bucket binning ==========
__global__ __launch_bounds__(256)
void k_bincnt(const int* __restrict__ dst, int* __restrict__ bucket_cnt,
              int E, int shift) {
  __shared__ int lcnt[512];
  int t = threadIdx.x;
  for (int i = t; i < 512; i += 256) lcnt[i] = 0;
  __syncthreads();
  int base = blockIdx.x * BINCH;
#pragma unroll
  for (int i = 0; i < 16; i++) {
    int e = base + t + i * 256;
    if (e < E) atomicAdd(&lcnt[dst[e] >> shift], 1);
  }
  __syncthreads();
  for (int b = t; b < 512; b += 256) {
    int c = lcnt[b];
    if (c > 0) atomicAdd(&bucket_cnt[b], c);
  }
}

__global__ void k_bscan(const int* __restrict__ bucket_cnt, int* __restrict__ bucket_base,
                        int* __restrict__ bucket_fill, int nbuc, int E) {
  __shared__ int s[512];
  int tid = threadIdx.x;
  int v = (tid < nbuc) ? bucket_cnt[tid] : 0;
  s[tid] = v;
  __syncthreads();
  for (int off = 1; off < 512; off <<= 1) {
    int tt = (tid >= off) ? s[tid - off] : 0;
    __syncthreads();
    s[tid] += tt;
    __syncthreads();
  }
  if (tid < nbuc) { int ex = s[tid] - v; bucket_base[tid] = ex; bucket_fill[tid] = ex; }
  if (tid == 0) bucket_base[nbuc] = E;
}

__global__ __launch_bounds__(256)
void k_binwrite(const int* __restrict__ src, const int* __restrict__ dst,
                int* __restrict__ bucket_fill, int* __restrict__ tsrc,
                int* __restrict__ tdst, int E, int shift) {
  __shared__ int lcnt[512];
  __shared__ int loff[512];
  int t = threadIdx.x;
  for (int i = t; i < 512; i += 256) lcnt[i] = 0;
  __syncthreads();
  int base = blockIdx.x * BINCH;
  int d[16], s_[16];
#pragma unroll
  for (int i = 0; i < 16; i++) {
    int e = base + t + i * 256;
    if (e < E) {
      d[i] = dst[e]; s_[i] = src[e];
      atomicAdd(&lcnt[d[i] >> shift], 1);
    } else d[i] = -1;
  }
  __syncthreads();
  for (int b = t; b < 512; b += 256) {
    int c = lcnt[b];
    loff[b] = (c > 0) ? atomicAdd(&bucket_fill[b], c) : 0;
  }
  __syncthreads();
#pragma unroll
  for (int i = 0; i < 16; i++) {
    if (d[i] >= 0) {
      int p = atomicAdd(&loff[d[i] >> shift], 1);
      tdst[p] = d[i];
      tsrc[p] = s_[i];
    }
  }
}

__global__ __launch_bounds__(256)
void k_deg2(const int* __restrict__ tdst, const int* __restrict__ bucket_base,
            int* __restrict__ deg, float* __restrict__ dinv, int N, int shift) {
  __shared__ int lcnt[1024];
  int b = blockIdx.x, t = threadIdx.x;
  int bs = 1 << shift, mask = bs - 1;
  for (int i = t; i < bs; i += 256) lcnt[i] = 0;
  __syncthreads();
  int r0 = bucket_base[b], r1 = bucket_base[b + 1];
  for (int e = r0 + t; e < r1; e += 256) atomicAdd(&lcnt[tdst[e] & mask], 1);
  __syncthreads();
  for (int i = t; i < bs; i += 256) {
    int node = (b << shift) + i;
    if (node < N) {
      deg[node] = lcnt[i];
      dinv[node] = rsqrtf((float)(lcnt[i] + 1));  // +1 self-loop
    }
  }
}

__global__ __launch_bounds__(256)
void k_csr2(const int* __restrict__ tsrc, const int* __restrict__ tdst,
            const int* __restrict__ bucket_base, const int* __restrict__ row_ptr,
            int* __restrict__ col_src, int N, int shift) {
  __shared__ int lrp[1024];
  __shared__ int lfill[1024];
  int b = blockIdx.x, t = threadIdx.x;
  int bs = 1 << shift, mask = bs - 1;
  for (int i = t; i < bs; i += 256) {
    int node = (b << shift) + i;
    lrp[i] = row_ptr[node < N ? node : N];
    lfill[i] = 0;
  }
  __syncthreads();
  int r0 = bucket_base[b], r1 = bucket_base[b + 1];
  for (int e = r0 + t; e < r1; e += 256) {
    int dl = tdst[e] & mask;
    int p = lrp[dl] + atomicAdd(&lfill[dl], 1);
    col_src[p] = tsrc[e];
  }
}

// ---------------- exclusive scan over node degrees (3-phase) ----------------
__global__ void k_scanA(const int* __restrict__ deg, int* __restrict__ row_ptr,
                        int* __restrict__ psum, int n) {
  __shared__ int s[256];
  int tid = threadIdx.x;
  int i = blockIdx.x * 256 + tid;
  int v = (i < n) ? deg[i] : 0;
  s[tid] = v;
  __syncthreads();
  for (int off = 1; off < 256; off <<= 1) {
    int t = (tid >= off) ? s[tid - off] : 0;
    __syncthreads();
    s[tid] += t;
    __syncthreads();
  }
  if (i < n) row_ptr[i] = s[tid] - v;
  if (tid == 255) psum[blockIdx.x] = s[255];
}

__global__ void k_scanB(int* psum, int nb) {
  __shared__ int s[512];
  int tid = threadIdx.x;
  int v = (tid < nb) ? psum[tid] : 0;
  s[tid] = v;
  __syncthreads();
  for (int off = 1; off < 512; off <<= 1) {
    int t = (tid >= off) ? s[tid - off] : 0;
    __syncthreads();
    s[tid] += t;
    __syncthreads();
  }
  if (tid < nb) psum[tid] = s[tid] - v;
}

__global__ void k_scanC(int* row_ptr, const int* __restrict__ psum, int n, int E) {
  int i = blockIdx.x * blockDim.x + threadIdx.x;
  if (i < n) row_ptr[i] += psum[i >> 8];
  if (i == 0) row_ptr[n] = E;
}

// ------- W1 cast: W1bf[col][k] = bf16(W1[k][col]), padded to 112 cols -------
__global__ void k_w1cast(const float* __restrict__ W1, unsigned short* __restrict__ W1bf) {
  int i = blockIdx.x * 256 + threadIdx.x;
  if (i >= NPAD * FDIM) return;
  int col = i / FDIM, k = i % FDIM;
  float v = (col < H1) ? W1[k * H1 + col] : 0.f;
  W1bf[i] = (unsigned short)f2bf_bits(v);
}

// ------ GEMM1 (MFMA): t1p[r][c] = bf16( (x@W1)[r][c] * dinv[r] ) ------------
// 512 thr = 8 waves, 128 rows/block. W (56KB bf16) staged in XOR-swizzled LDS
// so B is pipelined ds_read_b128 (R5: global-B at VGPR=40 -> serialized L2
// latency, 80us). A: 16 global float4 issued before the barrier (drain gives
// full MLP); asm memory-fence stops the scheduler sinking them.
__global__ __launch_bounds__(512, 2)
void k_gemm1m(const float* __restrict__ x, const unsigned short* __restrict__ W1bf,
              const float* __restrict__ dinv, unsigned short* __restrict__ t1p, int n) {
  __shared__ unsigned short ws[NPAD * FDIM];   // [col][k] bf16, swizzled
  int tid = threadIdx.x;
  int lane = tid & 63, w = tid >> 6;
  int lr = lane & 15, lg = lane >> 4;
  int r0 = blockIdx.x * 128 + w * 16;
  int arow = r0 + lr;
  const float* xrow = x + (size_t)(arow < n ? arow : 0) * FDIM;

  // issue A loads first: 16 independent float4, in flight across the barrier
  float4 va[16];
#pragma unroll
  for (int s = 0; s < 8; ++s) {
    int kb = s * 32 + lg * 8;
    va[2 * s]     = *(const float4*)(xrow + kb);
    va[2 * s + 1] = *(const float4*)(xrow + kb + 4);
  }

  // stage W: 3584 16B-chunks, 7 per thread, swizzled
  for (int i = tid; i < NPAD * FDIM / 8; i += 512) {
    int col = i >> 5;          // 32 chunks per col
    int kc = i & 31;           // chunk = 8 k
    uint4 v = *(const uint4*)(W1bf + col * FDIM + kc * 8);
    unsigned addr = (unsigned)(col * 512 + kc * 16) ^ ((unsigned)(col & 7) << 4);
    *(uint4*)((char*)ws + addr) = v;
  }
  asm volatile("" ::: "memory");   // keep A loads issued above this point
  __syncthreads();

  bf16x8 af[8];
#pragma unroll
  for (int s = 0; s < 8; ++s) {
    uint4 au;
    au.x = pack_bf16(va[2 * s].x, va[2 * s].y);
    au.y = pack_bf16(va[2 * s].z, va[2 * s].w);
    au.z = pack_bf16(va[2 * s + 1].x, va[2 * s + 1].y);
    au.w = pack_bf16(va[2 * s + 1].z, va[2 * s + 1].w);
    af[s] = *(bf16x8*)&au;
  }

  f32x4 acc[7];
#pragma unroll
  for (int nt = 0; nt < 7; nt++) acc[nt] = (f32x4){0.f, 0.f, 0.f, 0.f};

#pragma unroll
  for (int s = 0; s < 8; ++s) {
    int kb = s * 32 + lg * 8;
#pragma unroll
    for (int nt = 0; nt < 7; nt++) {
      int col = nt * 16 + lr;
      unsigned addr = (unsigned)(col * 512 + kb * 2) ^ ((unsigned)(col & 7) << 4);
      bf16x8 b = *(bf16x8*)((char*)ws + addr);
      acc[nt] = __builtin_amdgcn_mfma_f32_16x16x32_bf16(af[s], b, acc[nt], 0, 0, 0);
    }
  }

  // epilogue: D col = lane&15, row = (lane>>4)*4 + r
  float dv[4];
  int rbase = r0 + lg * 4;
#pragma unroll
  for (int r = 0; r < 4; r++) dv[r] = (rbase + r < n) ? dinv[rbase + r] : 0.f;
#pragma unroll
  for (int nt = 0; nt < 7; nt++) {
    int col = nt * 16 + lr;
    if (col < H1) {
#pragma unroll
      for (int r = 0; r < 4; r++) {
        int row = rbase + r;
        if (row < n)
          t1p[(size_t)row * H1 + col] = (unsigned short)f2bf_bits(acc[nt][r] * dv[r]);
      }
    }
  }
}

// ---- agg1: h[d] = bf16(relu(dinv[d]*(sum t1p[s] + t1p[d]) + b1)) -----------
__global__ __launch_bounds__(256)
void k_agg1(const unsigned* __restrict__ t1p, const int* __restrict__ row_ptr,
            const int* __restrict__ col_src, const float* __restrict__ dinv,
            const float* __restrict__ b1, unsigned* __restrict__ h, int n) {
  int wid = (int)((blockIdx.x * (size_t)blockDim.x + threadIdx.x) >> 6);
  if (wid >= n) return;
  int lane = threadIdx.x & 63;
  if (lane >= 50) return;
  int beg = row_ptr[wid], end = row_ptr[wid + 1];
  float a0 = 0.f, a1 = 0.f;
  for (int e = beg; e < end; e += 8) {
    int last = end - 1;
    int i1 = e + 1 < end ? e + 1 : last;
    int i2 = e + 2 < end ? e + 2 : last;
    int i3 = e + 3 < end ? e + 3 : last;
    int i4 = e + 4 < end ? e + 4 : last;
    int i5 = e + 5 < end ? e + 5 : last;
    int i6 = e + 6 < end ? e + 6 : last;
    int i7 = e + 7 < end ? e + 7 : last;
    int s0 = col_src[e],  s1 = col_src[i1], s2 = col_src[i2], s3 = col_src[i3];
    int s4 = col_src[i4], s5 = col_src[i5], s6 = col_src[i6], s7 = col_src[i7];
    unsigned u0 = t1p[(size_t)s0 * 50 + lane];
    unsigned u1 = t1p[(size_t)s1 * 50 + lane];
    unsigned u2 = t1p[(size_t)s2 * 50 + lane];
    unsigned u3 = t1p[(size_t)s3 * 50 + lane];
    unsigned u4 = t1p[(size_t)s4 * 50 + lane];
    unsigned u5 = t1p[(size_t)s5 * 50 + lane];
    unsigned u6 = t1p[(size_t)s6 * 50 + lane];
    unsigned u7 = t1p[(size_t)s7 * 50 + lane];
    a0 += bf_lo(u0); a1 += bf_hi(u0);
    if (e + 1 < end) { a0 += bf_lo(u1); a1 += bf_hi(u1); }
    if (e + 2 < end) { a0 += bf_lo(u2); a1 += bf_hi(u2); }
    if (e + 3 < end) { a0 += bf_lo(u3); a1 += bf_hi(u3); }
    if (e + 4 < end) { a0 += bf_lo(u4); a1 += bf_hi(u4); }
    if (e + 5 < end) { a0 += bf_lo(u5); a1 += bf_hi(u5); }
    if (e + 6 < end) { a0 += bf_lo(u6); a1 += bf_hi(u6); }
    if (e + 7 < end) { a0 += bf_lo(u7); a1 += bf_hi(u7); }
  }
  unsigned su = t1p[(size_t)wid * 50 + lane];
  a0 += bf_lo(su);
  a1 += bf_hi(su);
  float dv = dinv[wid];
  float v0 = fmaxf(dv * a0 + b1[2 * lane], 0.f);
  float v1 = fmaxf(dv * a1 + b1[2 * lane + 1], 0.f);
  h[(size_t)wid * 50 + lane] = pack_bf16(v0, v1);
}

// ------ GEMM2: t2p = bf16( (h @ W2) * dinv )  (N x 100 x 16) ----------------
__global__ __launch_bounds__(256)
void k_gemm2(const unsigned* __restrict__ h, const float* __restrict__ W2,
             const float* __restrict__ dinv, unsigned* __restrict__ t2p, int n) {
  __shared__ alignas(16) float w2s[100][16];
  __shared__ float hs[64][101];
  int tid = threadIdx.x;
  int r0 = blockIdx.x * 64;
  for (int idx = tid; idx < H1 * H2; idx += 256) w2s[idx / 16][idx % 16] = W2[idx];
  for (int idx = tid; idx < 64 * 50; idx += 256) {
    int row = idx / 50, u = idx % 50;
    int gr = r0 + row;
    unsigned v = 0;
    if (gr < n) v = h[(size_t)gr * 50 + u];
    hs[row][2 * u + 0] = bf_lo(v);
    hs[row][2 * u + 1] = bf_hi(v);
  }
  __syncthreads();
  int r = tid & 63, cg = tid >> 6;
  float ax = 0.f, ay = 0.f, az = 0.f, aw = 0.f;
#pragma unroll 4
  for (int k = 0; k < H1; ++k) {
    float a = hs[r][k];
    float4 w = *(const float4*)&w2s[k][cg * 4];
    ax += a * w.x; ay += a * w.y; az += a * w.z; aw += a * w.w;
  }
  int gr = r0 + r;
  if (gr < n) {
    float dv = dinv[gr];
    unsigned u0 = pack_bf16(ax * dv, ay * dv);
    unsigned u1 = pack_bf16(az * dv, aw * dv);
    *(uint2*)(t2p + (size_t)gr * 8 + cg * 2) = make_uint2(u0, u1);
  }
}

// ------- agg2 + bias + relu + row-normalize: emb (N x 16, f32) --------------
__global__ __launch_bounds__(256)
void k_agg2(const unsigned* __restrict__ t2p, const int* __restrict__ row_ptr,
            const int* __restrict__ col_src, const float* __restrict__ dinv,
            const float* __restrict__ b2, float* __restrict__ emb, int n) {
  int wid = (int)((blockIdx.x * (size_t)blockDim.x + threadIdx.x) >> 6);
  if (wid >= n) return;
  int lane = threadIdx.x & 63;
  int es = lane >> 3, c = lane & 7;
  int beg = row_ptr[wid], end = row_ptr[wid + 1];
  float a0 = 0.f, a1 = 0.f;
  for (int e = beg + es; e < end; e += 8) {
    int s = col_src[e];
    unsigned u = t2p[(size_t)s * 8 + c];
    a0 += bf_lo(u);
    a1 += bf_hi(u);
  }
  a0 += __shfl_xor(a0, 8, 64);  a1 += __shfl_xor(a1, 8, 64);
  a0 += __shfl_xor(a0, 16, 64); a1 += __shfl_xor(a1, 16, 64);
  a0 += __shfl_xor(a0, 32, 64); a1 += __shfl_xor(a1, 32, 64);
  unsigned su = t2p[(size_t)wid * 8 + c];
  a0 += bf_lo(su);
  a1 += bf_hi(su);
  float dv = dinv[wid];
  float v0 = fmaxf(dv * a0 + b2[2 * c + 0], 0.f);
  float v1 = fmaxf(dv * a1 + b2[2 * c + 1], 0.f);
  float n2 = v0 * v0 + v1 * v1;
  n2 += __shfl_xor(n2, 1, 64);
  n2 += __shfl_xor(n2, 2, 64);
  n2 += __shfl_xor(n2, 4, 64);
  float scale = 1.f / fmaxf(sqrtf(n2), 1.f);
  if (es == 0) {
    *(float2*)(emb + (size_t)wid * H2 + 2 * c) = make_float2(v0 * scale, v1 * scale);
  }
}

// ---------------- edge scorer (MFMA over K=64-padded 41 features) -----------
// wave = 16 edges. A row=edge(lr), k-block=lg: lg0/1=sqdist, lg2/3+a1=PI.
// D: col(j)=lr (+16 for nt1), row=edge=lg*4+r. 2nd layer via 16-lane shfl.
__global__ __launch_bounds__(256)
void k_score(const float* __restrict__ emb, const int* __restrict__ te,
             const float* __restrict__ PI, const float* __restrict__ l1W,
             const float* __restrict__ l1b, const float* __restrict__ lW,
             const float* __restrict__ lb, float* __restrict__ out, int ned) {
  int tid = threadIdx.x;
  int lane = tid & 63, w = tid >> 6;
  int lr = lane & 15, lg = lane >> 4;
  int e0w = blockIdx.x * 64 + w * 16;
  int e = e0w + lr;
  int ec = (e < ned) ? e : 0;

  // ---- B fragments (one-time, small): B[col=j][k] = l1W[k*25+j] ----
  float wb[16];
#pragma unroll
  for (int i = 0; i < 8; i++) {
    int k0 = lg * 8 + i;          // < 32 <= 41: always valid
    wb[i] = (lr < 25) ? l1W[k0 * 25 + lr] : 0.f;
    int k1 = 32 + lg * 8 + i;
    wb[8 + i] = (lr < 25 && k1 < 41) ? l1W[k1 * 25 + lr] : 0.f;
  }
  int j1 = 16 + lr;
  float wb2[16];
#pragma unroll
  for (int i = 0; i < 8; i++) {
    int k0 = lg * 8 + i;
    wb2[i] = (j1 < 25) ? l1W[k0 * 25 + j1] : 0.f;
    int k1 = 32 + lg * 8 + i;
    wb2[8 + i] = (j1 < 25 && k1 < 41) ? l1W[k1 * 25 + j1] : 0.f;
  }
  uint4 B00, B01, B10, B11;
  B00.x = pack_bf16(wb[0], wb[1]);  B00.y = pack_bf16(wb[2], wb[3]);
  B00.z = pack_bf16(wb[4], wb[5]);  B00.w = pack_bf16(wb[6], wb[7]);
  B01.x = pack_bf16(wb[8], wb[9]);  B01.y = pack_bf16(wb[10], wb[11]);
  B01.z = pack_bf16(wb[12], wb[13]); B01.w = pack_bf16(wb[14], wb[15]);
  B10.x = pack_bf16(wb2[0], wb2[1]); B10.y = pack_bf16(wb2[2], wb2[3]);
  B10.z = pack_bf16(wb2[4], wb2[5]); B10.w = pack_bf16(wb2[6], wb2[7]);
  B11.x = pack_bf16(wb2[8], wb2[9]); B11.y = pack_bf16(wb2[10], wb2[11]);
  B11.z = pack_bf16(wb2[12], wb2[13]); B11.w = pack_bf16(wb2[14], wb2[15]);

  // ---- A fragments for this lane's edge ----
  uint4 A0 = {0u, 0u, 0u, 0u}, A1 = {0u, 0u, 0u, 0u};
  const float* pie = PI + (size_t)ec * 25;
  if (lg < 2) {
    int2 uv = *(const int2*)(te + 2 * (size_t)ec);
    const float* eu = emb + (size_t)uv.x * H2 + lg * 8;
    const float* ev = emb + (size_t)uv.y * H2 + lg * 8;
    float4 a0 = *(const float4*)(eu);
    float4 a1 = *(const float4*)(eu + 4);
    float4 b0 = *(const float4*)(ev);
    float4 b1 = *(const float4*)(ev + 4);
    float d0 = a0.x - b0.x, d1 = a0.y - b0.y, d2 = a0.z - b0.z, d3 = a0.w - b0.w;
    float d4 = a1.x - b1.x, d5 = a1.y - b1.y, d6 = a1.z - b1.z, d7 = a1.w - b1.w;
    A0.x = pack_bf16(d0 * d0, d1 * d1);
    A0.y = pack_bf16(d2 * d2, d3 * d3);
    A0.z = pack_bf16(d4 * d4, d5 * d5);
    A0.w = pack_bf16(d6 * d6, d7 * d7);
    if (lg == 0) {  // a1: k=32..39 -> PI[16..23]
      f32x4a p0 = *(const f32x4a*)(pie + 16);
      f32x4a p1 = *(const f32x4a*)(pie + 20);
      A1.x = pack_bf16(p0[0], p0[1]); A1.y = pack_bf16(p0[2], p0[3]);
      A1.z = pack_bf16(p1[0], p1[1]); A1.w = pack_bf16(p1[2], p1[3]);
    } else {        // a1: k=40 -> PI[24], rest 0
      A1.x = pack_bf16(pie[24], 0.f);
    }
  } else if (lg == 2) {  // a0: k=16..23 -> PI[0..7]
    f32x4a p0 = *(const f32x4a*)(pie);
    f32x4a p1 = *(const f32x4a*)(pie + 4);
    A0.x = pack_bf16(p0[0], p0[1]); A0.y = pack_bf16(p0[2], p0[3]);
    A0.z = pack_bf16(p1[0], p1[1]); A0.w = pack_bf16(p1[2], p1[3]);
  } else {               // a0: k=24..31 -> PI[8..15]
    f32x4a p0 = *(const f32x4a*)(pie + 8);
    f32x4a p1 = *(const f32x4a*)(pie + 12);
    A0.x = pack_bf16(p0[0], p0[1]); A0.y = pack_bf16(p0[2], p0[3]);
    A0.z = pack_bf16(p1[0], p1[1]); A0.w = pack_bf16(p1[2], p1[3]);
  }

  f32x4 acc0 = {0.f, 0.f, 0.f, 0.f}, acc1 = {0.f, 0.f, 0.f, 0.f};
  acc0 = __builtin_amdgcn_mfma_f32_16x16x32_bf16(*(bf16x8*)&A0, *(bf16x8*)&B00, acc0, 0, 0, 0);
  acc0 = __builtin_amdgcn_mfma_f32_16x16x32_bf16(*(bf16x8*)&A1, *(bf16x8*)&B01, acc0, 0, 0, 0);
  acc1 = __builtin_amdgcn_mfma_f32_16x16x32_bf16(*(bf16x8*)&A0, *(bf16x8*)&B10, acc1, 0, 0, 0);
  acc1 = __builtin_amdgcn_mfma_f32_16x16x32_bf16(*(bf16x8*)&A1, *(bf16x8*)&B11, acc1, 0, 0, 0);

  // ---- epilogue: leaky-relu + 2nd layer, reduce over j (lr lanes) ----
  float bj0 = l1b[lr];                       // lr < 16 < 25 always valid
  float wj0 = lW[lr];
  float bj1 = (j1 < 25) ? l1b[j1] : 0.f;
  float wj1 = (j1 < 25) ? lW[j1] : 0.f;
  float lbv = lb[0];
  float part[4];
#pragma unroll
  for (int r = 0; r < 4; r++) {
    float a0v = acc0[r] + bj0;
    a0v = (a0v > 0.f) ? a0v : 0.2f * a0v;
    float a1v = acc1[r] + bj1;
    a1v = (a1v > 0.f) ? a1v : 0.2f * a1v;
    part[r] = a0v * wj0 + ((j1 < 25) ? a1v * wj1 : 0.f);
  }
#pragma unroll
  for (int r = 0; r < 4; r++) {
    part[r] += __shfl_xor(part[r], 1, 64);
    part[r] += __shfl_xor(part[r], 2, 64);
    part[r] += __shfl_xor(part[r], 4, 64);
    part[r] += __shfl_xor(part[r], 8, 64);
  }
  if (lr == 0) {
#pragma unroll
    for (int r = 0; r < 4; r++) {
      int eo = e0w + lg * 4 + r;
      if (eo < ned) {
        float s = fminf(fabsf(part[r] + lbv), 40.f);
        float z = 2.f - s;
        out[eo] = 1.f / (1.f + __expf(-z));
      }
    }
  }
}

// ---------------- launch -----------------------------------------------------
extern "C" void kernel_launch(void* const* d_in, const int* in_sizes, int n_in,
                              void* d_out, int out_size, void* d_ws, size_t ws_size,
                              hipStream_t stream) {
  const float* x   = (const float*)d_in[0];
  const int*   ei  = (const int*)d_in[1];
  const int*   te  = (const int*)d_in[2];
  const float* PI  = (const float*)d_in[3];
  const float* W1  = (const float*)d_in[4];
  const float* b1  = (const float*)d_in[5];
  const float* W2  = (const float*)d_in[6];
  const float* b2  = (const float*)d_in[7];
  const float* l1W = (const float*)d_in[8];
  const float* l1b = (const float*)d_in[9];
  const float* lW  = (const float*)d_in[10];
  const float* lb  = (const float*)d_in[11];
  float* out = (float*)d_out;

  int h1 = in_sizes[5];            // 100
  int F  = in_sizes[4] / h1;       // 256
  int N  = in_sizes[0] / F;        // 100000
  int E  = in_sizes[1] / 2;        // 1600000
  int ED = in_sizes[2] / 2;        // 1000000

  const int* src  = ei;
  const int* dstp = ei + E;

  int shift = 8;
  while ((((size_t)N + ((size_t)1 << shift) - 1) >> shift) > 512) shift++;
  int nbuc = (N + (1 << shift) - 1) >> shift;

  size_t off = 0;
  auto alloc = [&](size_t bytes) -> void* {
    void* p = (char*)d_ws + off;
    off += (bytes + 255) & ~(size_t)255;
    return p;
  };
  int*            deg      = (int*)alloc((size_t)N * 4);
  float*          dinv     = (float*)alloc((size_t)N * 4);
  int*            row_ptr  = (int*)alloc((size_t)(N + 1) * 4);
  int*            psum     = (int*)alloc(512 * 4);
  int*            bcnt     = (int*)alloc(512 * 4);
  int*            bbase    = (int*)alloc(520 * 4);
  int*            bfill    = (int*)alloc(512 * 4);
  int*            col_src  = (int*)alloc((size_t)E * 4);
  unsigned short* W1bf     = (unsigned short*)alloc((size_t)NPAD * FDIM * 2);
  unsigned*       t1p      = (unsigned*)alloc((size_t)N * 50 * 4);  // bf16 x2 packed
  unsigned*       h        = (unsigned*)alloc((size_t)N * 50 * 4);
  unsigned*       t2p      = (unsigned*)alloc((size_t)N * 8 * 4);
  float*          emb      = (float*)alloc((size_t)N * H2 * 4);

  int* tdst = (int*)h;             // temp binned edges alias h (dead until agg1)
  int* tsrc = (int*)h + E;

  int nb = (N + 255) / 256;
  int nwb = (E + BINCH - 1) / BINCH;

  hipMemsetAsync(bcnt, 0, 512 * 4, stream);
  k_bincnt<<<nwb, 256, 0, stream>>>(dstp, bcnt, E, shift);
  k_bscan<<<1, 512, 0, stream>>>(bcnt, bbase, bfill, nbuc, E);
  k_binwrite<<<nwb, 256, 0, stream>>>(src, dstp, bfill, tsrc, tdst, E, shift);
  k_deg2<<<nbuc, 256, 0, stream>>>(tdst, bbase, deg, dinv, N, shift);
  k_scanA<<<nb, 256, 0, stream>>>(deg, row_ptr, psum, N);
  k_scanB<<<1, 512, 0, stream>>>(psum, nb);
  k_scanC<<<nb, 256, 0, stream>>>(row_ptr, psum, N, E);
  k_csr2<<<nbuc, 256, 0, stream>>>(tsrc, tdst, bbase, row_ptr, col_src, N, shift);
  k_w1cast<<<(NPAD * FDIM + 255) / 256, 256, 0, stream>>>(W1, W1bf);
  k_gemm1m<<<(N + 127) / 128, 512, 0, stream>>>(x, W1bf, dinv, (unsigned short*)t1p, N);
  k_agg1<<<(int)(((size_t)N * 64 + 255) / 256), 256, 0, stream>>>(t1p, row_ptr, col_src, dinv, b1, h, N);
  k_gemm2<<<(N + 63) / 64, 256, 0, stream>>>(h, W2, dinv, t2p, N);
  k_agg2<<<(int)(((size_t)N * 64 + 255) / 256), 256, 0, stream>>>(t2p, row_ptr, col_src, dinv, b2, emb, N);
  k_score<<<(ED + 63) / 64, 256, 0, stream>>>(emb, te, PI, l1W, l1b, lW, lb, out, ED);
}

// Round 8
// 306.193 us; speedup vs baseline: 1.3567x; 1.0353x over previous
//
#include <hip/hip_runtime.h>
#include <hip/hip_bf16.h>
#include <math.h>

#define H1 100
#define H2 16
#define FDIM 256
#define NPAD 112   // H1 padded to 7*16
#define BINCH 4096 // edges per binning workgroup

typedef __attribute__((ext_vector_type(8))) short bf16x8;
typedef __attribute__((ext_vector_type(4))) float f32x4;
typedef float f32x4a __attribute__((ext_vector_type(4), aligned(4)));  // 4B-aligned vec load

// ---- bf16 pack/unpack helpers (bit-exact unpack, RNE pack) ----
__device__ __forceinline__ float bf_lo(unsigned u) { return __uint_as_float(u << 16); }
__device__ __forceinline__ float bf_hi(unsigned u) { return __uint_as_float(u & 0xffff0000u); }
__device__ __forceinline__ unsigned f2bf_bits(float f) {
  unsigned x = __float_as_uint(f);
  return (x + 0x7fffu + ((x >> 16) & 1u)) >> 16;   // round-nearest-even
}
__device__ __forceinline__ unsigned pack_bf16(float a, float b) {
  return f2bf_bits(a) | (f2bf_bits(b) << 16);
}

// ============ CSR build via bucket binning ==========
__global__ __launch_bounds__(256)
void k_bincnt(const int* __restrict__ dst, int* __restrict__ bucket_cnt,
              int E, int shift) {
  __shared__ int lcnt[512];
  int t = threadIdx.x;
  for (int i = t; i < 512; i += 256) lcnt[i] = 0;
  __syncthreads();
  int base = blockIdx.x * BINCH;
#pragma unroll
  for (int i = 0; i < 16; i++) {
    int e = base + t + i * 256;
    if (e < E) atomicAdd(&lcnt[dst[e] >> shift], 1);
  }
  __syncthreads();
  for (int b = t; b < 512; b += 256) {
    int c = lcnt[b];
    if (c > 0) atomicAdd(&bucket_cnt[b], c);
  }
}

__global__ void k_bscan(const int* __restrict__ bucket_cnt, int* __restrict__ bucket_base,
                        int* __restrict__ bucket_fill, int nbuc, int E) {
  __shared__ int s[512];
  int tid = threadIdx.x;
  int v = (tid < nbuc) ? bucket_cnt[tid] : 0;
  s[tid] = v;
  __syncthreads();
  for (int off = 1; off < 512; off <<= 1) {
    int tt = (tid >= off) ? s[tid - off] : 0;
    __syncthreads();
    s[tid] += tt;
    __syncthreads();
  }
  if (tid < nbuc) { int ex = s[tid] - v; bucket_base[tid] = ex; bucket_fill[tid] = ex; }
  if (tid == 0) bucket_base[nbuc] = E;
}

__global__ __launch_bounds__(256)
void k_binwrite(const int* __restrict__ src, const int* __restrict__ dst,
                int* __restrict__ bucket_fill, int* __restrict__ tsrc,
                int* __restrict__ tdst, int E, int shift) {
  __shared__ int lcnt[512];
  __shared__ int loff[512];
  int t = threadIdx.x;
  for (int i = t; i < 512; i += 256) lcnt[i] = 0;
  __syncthreads();
  int base = blockIdx.x * BINCH;
  int d[16], s_[16];
#pragma unroll
  for (int i = 0; i < 16; i++) {
    int e = base + t + i * 256;
    if (e < E) {
      d[i] = dst[e]; s_[i] = src[e];
      atomicAdd(&lcnt[d[i] >> shift], 1);
    } else d[i] = -1;
  }
  __syncthreads();
  for (int b = t; b < 512; b += 256) {
    int c = lcnt[b];
    loff[b] = (c > 0) ? atomicAdd(&bucket_fill[b], c) : 0;
  }
  __syncthreads();
#pragma unroll
  for (int i = 0; i < 16; i++) {
    if (d[i] >= 0) {
      int p = atomicAdd(&loff[d[i] >> shift], 1);
      tdst[p] = d[i];
      tsrc[p] = s_[i];
    }
  }
}

__global__ __launch_bounds__(256)
void k_deg2(const int* __restrict__ tdst, const int* __restrict__ bucket_base,
            int* __restrict__ deg, float* __restrict__ dinv, int N, int shift) {
  __shared__ int lcnt[1024];
  int b = blockIdx.x, t = threadIdx.x;
  int bs = 1 << shift, mask = bs - 1;
  for (int i = t; i < bs; i += 256) lcnt[i] = 0;
  __syncthreads();
  int r0 = bucket_base[b], r1 = bucket_base[b + 1];
  for (int e = r0 + t; e < r1; e += 256) atomicAdd(&lcnt[tdst[e] & mask], 1);
  __syncthreads();
  for (int i = t; i < bs; i += 256) {
    int node = (b << shift) + i;
    if (node < N) {
      deg[node] = lcnt[i];
      dinv[node] = rsqrtf((float)(lcnt[i] + 1));  // +1 self-loop
    }
  }
}

__global__ __launch_bounds__(256)
void k_csr2(const int* __restrict__ tsrc, const int* __restrict__ tdst,
            const int* __restrict__ bucket_base, const int* __restrict__ row_ptr,
            int* __restrict__ col_src, int N, int shift) {
  __shared__ int lrp[1024];
  __shared__ int lfill[1024];
  int b = blockIdx.x, t = threadIdx.x;
  int bs = 1 << shift, mask = bs - 1;
  for (int i = t; i < bs; i += 256) {
    int node = (b << shift) + i;
    lrp[i] = row_ptr[node < N ? node : N];
    lfill[i] = 0;
  }
  __syncthreads();
  int r0 = bucket_base[b], r1 = bucket_base[b + 1];
  for (int e = r0 + t; e < r1; e += 256) {
    int dl = tdst[e] & mask;
    int p = lrp[dl] + atomicAdd(&lfill[dl], 1);
    col_src[p] = tsrc[e];
  }
}

// ---------------- exclusive scan over node degrees (3-phase) ----------------
__global__ void k_scanA(const int* __restrict__ deg, int* __restrict__ row_ptr,
                        int* __restrict__ psum, int n) {
  __shared__ int s[256];
  int tid = threadIdx.x;
  int i = blockIdx.x * 256 + tid;
  int v = (i < n) ? deg[i] : 0;
  s[tid] = v;
  __syncthreads();
  for (int off = 1; off < 256; off <<= 1) {
    int t = (tid >= off) ? s[tid - off] : 0;
    __syncthreads();
    s[tid] += t;
    __syncthreads();
  }
  if (i < n) row_ptr[i] = s[tid] - v;
  if (tid == 255) psum[blockIdx.x] = s[255];
}

__global__ void k_scanB(int* psum, int nb) {
  __shared__ int s[512];
  int tid = threadIdx.x;
  int v = (tid < nb) ? psum[tid] : 0;
  s[tid] = v;
  __syncthreads();
  for (int off = 1; off < 512; off <<= 1) {
    int t = (tid >= off) ? s[tid - off] : 0;
    __syncthreads();
    s[tid] += t;
    __syncthreads();
  }
  if (tid < nb) psum[tid] = s[tid] - v;
}

__global__ void k_scanC(int* row_ptr, const int* __restrict__ psum, int n, int E) {
  int i = blockIdx.x * blockDim.x + threadIdx.x;
  if (i < n) row_ptr[i] += psum[i >> 8];
  if (i == 0) row_ptr[n] = E;
}

// ------- W1 cast: W1bf[col][k] = bf16(W1[k][col]), padded to 112 cols -------
__global__ void k_w1cast(const float* __restrict__ W1, unsigned short* __restrict__ W1bf) {
  int i = blockIdx.x * 256 + threadIdx.x;
  if (i >= NPAD * FDIM) return;
  int col = i / FDIM, k = i % FDIM;
  float v = (col < H1) ? W1[k * H1 + col] : 0.f;
  W1bf[i] = (unsigned short)f2bf_bits(v);
}

// ------ GEMM1 (MFMA): t1p[r][c] = bf16( (x@W1)[r][c] * dinv[r] ) ------------
__global__ __launch_bounds__(512, 2)
void k_gemm1m(const float* __restrict__ x, const unsigned short* __restrict__ W1bf,
              const float* __restrict__ dinv, unsigned short* __restrict__ t1p, int n) {
  __shared__ unsigned short ws[NPAD * FDIM];   // [col][k] bf16, swizzled
  int tid = threadIdx.x;
  int lane = tid & 63, w = tid >> 6;
  int lr = lane & 15, lg = lane >> 4;
  int r0 = blockIdx.x * 128 + w * 16;
  int arow = r0 + lr;
  const float* xrow = x + (size_t)(arow < n ? arow : 0) * FDIM;

  // issue A loads first: 16 independent float4, in flight across the barrier
  float4 va[16];
#pragma unroll
  for (int s = 0; s < 8; ++s) {
    int kb = s * 32 + lg * 8;
    va[2 * s]     = *(const float4*)(xrow + kb);
    va[2 * s + 1] = *(const float4*)(xrow + kb + 4);
  }

  // stage W: 3584 16B-chunks, 7 per thread, swizzled
  for (int i = tid; i < NPAD * FDIM / 8; i += 512) {
    int col = i >> 5;          // 32 chunks per col
    int kc = i & 31;           // chunk = 8 k
    uint4 v = *(const uint4*)(W1bf + col * FDIM + kc * 8);
    unsigned addr = (unsigned)(col * 512 + kc * 16) ^ ((unsigned)(col & 7) << 4);
    *(uint4*)((char*)ws + addr) = v;
  }
  asm volatile("" ::: "memory");   // keep A loads issued above this point
  __syncthreads();

  bf16x8 af[8];
#pragma unroll
  for (int s = 0; s < 8; ++s) {
    uint4 au;
    au.x = pack_bf16(va[2 * s].x, va[2 * s].y);
    au.y = pack_bf16(va[2 * s].z, va[2 * s].w);
    au.z = pack_bf16(va[2 * s + 1].x, va[2 * s + 1].y);
    au.w = pack_bf16(va[2 * s + 1].z, va[2 * s + 1].w);
    af[s] = *(bf16x8*)&au;
  }

  f32x4 acc[7];
#pragma unroll
  for (int nt = 0; nt < 7; nt++) acc[nt] = (f32x4){0.f, 0.f, 0.f, 0.f};

#pragma unroll
  for (int s = 0; s < 8; ++s) {
    int kb = s * 32 + lg * 8;
#pragma unroll
    for (int nt = 0; nt < 7; nt++) {
      int col = nt * 16 + lr;
      unsigned addr = (unsigned)(col * 512 + kb * 2) ^ ((unsigned)(col & 7) << 4);
      bf16x8 b = *(bf16x8*)((char*)ws + addr);
      acc[nt] = __builtin_amdgcn_mfma_f32_16x16x32_bf16(af[s], b, acc[nt], 0, 0, 0);
    }
  }

  // epilogue: D col = lane&15, row = (lane>>4)*4 + r
  float dv[4];
  int rbase = r0 + lg * 4;
#pragma unroll
  for (int r = 0; r < 4; r++) dv[r] = (rbase + r < n) ? dinv[rbase + r] : 0.f;
#pragma unroll
  for (int nt = 0; nt < 7; nt++) {
    int col = nt * 16 + lr;
    if (col < H1) {
#pragma unroll
      for (int r = 0; r < 4; r++) {
        int row = rbase + r;
        if (row < n)
          t1p[(size_t)row * H1 + col] = (unsigned short)f2bf_bits(acc[nt][r] * dv[r]);
      }
    }
  }
}

// ---- agg1: h[d] = bf16(relu(dinv[d]*(sum t1p[s] + t1p[d]) + b1)) -----------
__global__ __launch_bounds__(256)
void k_agg1(const unsigned* __restrict__ t1p, const int* __restrict__ row_ptr,
            const int* __restrict__ col_src, const float* __restrict__ dinv,
            const float* __restrict__ b1, unsigned* __restrict__ h, int n) {
  int wid = (int)((blockIdx.x * (size_t)blockDim.x + threadIdx.x) >> 6);
  if (wid >= n) return;
  int lane = threadIdx.x & 63;
  if (lane >= 50) return;
  int beg = row_ptr[wid], end = row_ptr[wid + 1];
  float a0 = 0.f, a1 = 0.f;
  for (int e = beg; e < end; e += 8) {
    int last = end - 1;
    int i1 = e + 1 < end ? e + 1 : last;
    int i2 = e + 2 < end ? e + 2 : last;
    int i3 = e + 3 < end ? e + 3 : last;
    int i4 = e + 4 < end ? e + 4 : last;
    int i5 = e + 5 < end ? e + 5 : last;
    int i6 = e + 6 < end ? e + 6 : last;
    int i7 = e + 7 < end ? e + 7 : last;
    int s0 = col_src[e],  s1 = col_src[i1], s2 = col_src[i2], s3 = col_src[i3];
    int s4 = col_src[i4], s5 = col_src[i5], s6 = col_src[i6], s7 = col_src[i7];
    unsigned u0 = t1p[(size_t)s0 * 50 + lane];
    unsigned u1 = t1p[(size_t)s1 * 50 + lane];
    unsigned u2 = t1p[(size_t)s2 * 50 + lane];
    unsigned u3 = t1p[(size_t)s3 * 50 + lane];
    unsigned u4 = t1p[(size_t)s4 * 50 + lane];
    unsigned u5 = t1p[(size_t)s5 * 50 + lane];
    unsigned u6 = t1p[(size_t)s6 * 50 + lane];
    unsigned u7 = t1p[(size_t)s7 * 50 + lane];
    a0 += bf_lo(u0); a1 += bf_hi(u0);
    if (e + 1 < end) { a0 += bf_lo(u1); a1 += bf_hi(u1); }
    if (e + 2 < end) { a0 += bf_lo(u2); a1 += bf_hi(u2); }
    if (e + 3 < end) { a0 += bf_lo(u3); a1 += bf_hi(u3); }
    if (e + 4 < end) { a0 += bf_lo(u4); a1 += bf_hi(u4); }
    if (e + 5 < end) { a0 += bf_lo(u5); a1 += bf_hi(u5); }
    if (e + 6 < end) { a0 += bf_lo(u6); a1 += bf_hi(u6); }
    if (e + 7 < end) { a0 += bf_lo(u7); a1 += bf_hi(u7); }
  }
  unsigned su = t1p[(size_t)wid * 50 + lane];
  a0 += bf_lo(su);
  a1 += bf_hi(su);
  float dv = dinv[wid];
  float v0 = fmaxf(dv * a0 + b1[2 * lane], 0.f);
  float v1 = fmaxf(dv * a1 + b1[2 * lane + 1], 0.f);
  h[(size_t)wid * 50 + lane] = pack_bf16(v0, v1);
}

// ------ GEMM2: t2p = bf16( (h @ W2) * dinv )  (N x 100 x 16) ----------------
__global__ __launch_bounds__(256)
void k_gemm2(const unsigned* __restrict__ h, const float* __restrict__ W2,
             const float* __restrict__ dinv, unsigned* __restrict__ t2p, int n) {
  __shared__ alignas(16) float w2s[100][16];
  __shared__ float hs[64][101];
  int tid = threadIdx.x;
  int r0 = blockIdx.x * 64;
  for (int idx = tid; idx < H1 * H2; idx += 256) w2s[idx / 16][idx % 16] = W2[idx];
  for (int idx = tid; idx < 64 * 50; idx += 256) {
    int row = idx / 50, u = idx % 50;
    int gr = r0 + row;
    unsigned v = 0;
    if (gr < n) v = h[(size_t)gr * 50 + u];
    hs[row][2 * u + 0] = bf_lo(v);
    hs[row][2 * u + 1] = bf_hi(v);
  }
  __syncthreads();
  int r = tid & 63, cg = tid >> 6;
  float ax = 0.f, ay = 0.f, az = 0.f, aw = 0.f;
#pragma unroll 4
  for (int k = 0; k < H1; ++k) {
    float a = hs[r][k];
    float4 w = *(const float4*)&w2s[k][cg * 4];
    ax += a * w.x; ay += a * w.y; az += a * w.z; aw += a * w.w;
  }
  int gr = r0 + r;
  if (gr < n) {
    float dv = dinv[gr];
    unsigned u0 = pack_bf16(ax * dv, ay * dv);
    unsigned u1 = pack_bf16(az * dv, aw * dv);
    *(uint2*)(t2p + (size_t)gr * 8 + cg * 2) = make_uint2(u0, u1);
  }
}

// ------- agg2 + bias + relu + row-normalize: emb (N x 16, f32) --------------
__global__ __launch_bounds__(256)
void k_agg2(const unsigned* __restrict__ t2p, const int* __restrict__ row_ptr,
            const int* __restrict__ col_src, const float* __restrict__ dinv,
            const float* __restrict__ b2, float* __restrict__ emb, int n) {
  int wid = (int)((blockIdx.x * (size_t)blockDim.x + threadIdx.x) >> 6);
  if (wid >= n) return;
  int lane = threadIdx.x & 63;
  int es = lane >> 3, c = lane & 7;
  int beg = row_ptr[wid], end = row_ptr[wid + 1];
  float a0 = 0.f, a1 = 0.f;
  for (int e = beg + es; e < end; e += 8) {
    int s = col_src[e];
    unsigned u = t2p[(size_t)s * 8 + c];
    a0 += bf_lo(u);
    a1 += bf_hi(u);
  }
  a0 += __shfl_xor(a0, 8, 64);  a1 += __shfl_xor(a1, 8, 64);
  a0 += __shfl_xor(a0, 16, 64); a1 += __shfl_xor(a1, 16, 64);
  a0 += __shfl_xor(a0, 32, 64); a1 += __shfl_xor(a1, 32, 64);
  unsigned su = t2p[(size_t)wid * 8 + c];
  a0 += bf_lo(su);
  a1 += bf_hi(su);
  float dv = dinv[wid];
  float v0 = fmaxf(dv * a0 + b2[2 * c + 0], 0.f);
  float v1 = fmaxf(dv * a1 + b2[2 * c + 1], 0.f);
  float n2 = v0 * v0 + v1 * v1;
  n2 += __shfl_xor(n2, 1, 64);
  n2 += __shfl_xor(n2, 2, 64);
  n2 += __shfl_xor(n2, 4, 64);
  float scale = 1.f / fmaxf(sqrtf(n2), 1.f);
  if (es == 0) {
    *(float2*)(emb + (size_t)wid * H2 + 2 * c) = make_float2(v0 * scale, v1 * scale);
  }
}

// ---- scorer B-fragment precompute: one-time, 64 threads ----
// Bt[lane*4 + {0,1,2,3}] = {B00,B01,B10,B11} for that lane (edge-invariant).
__global__ void k_sprep(const float* __restrict__ l1W, uint4* __restrict__ Bt) {
  int lane = threadIdx.x;   // 0..63
  int lr = lane & 15, lg = lane >> 4;
  float wb[16];
#pragma unroll
  for (int i = 0; i < 8; i++) {
    int k0 = lg * 8 + i;
    wb[i] = (lr < 25) ? l1W[k0 * 25 + lr] : 0.f;
    int k1 = 32 + lg * 8 + i;
    wb[8 + i] = (lr < 25 && k1 < 41) ? l1W[k1 * 25 + lr] : 0.f;
  }
  int j1 = 16 + lr;
  float wb2[16];
#pragma unroll
  for (int i = 0; i < 8; i++) {
    int k0 = lg * 8 + i;
    wb2[i] = (j1 < 25) ? l1W[k0 * 25 + j1] : 0.f;
    int k1 = 32 + lg * 8 + i;
    wb2[8 + i] = (j1 < 25 && k1 < 41) ? l1W[k1 * 25 + j1] : 0.f;
  }
  uint4 B00, B01, B10, B11;
  B00.x = pack_bf16(wb[0], wb[1]);  B00.y = pack_bf16(wb[2], wb[3]);
  B00.z = pack_bf16(wb[4], wb[5]);  B00.w = pack_bf16(wb[6], wb[7]);
  B01.x = pack_bf16(wb[8], wb[9]);  B01.y = pack_bf16(wb[10], wb[11]);
  B01.z = pack_bf16(wb[12], wb[13]); B01.w = pack_bf16(wb[14], wb[15]);
  B10.x = pack_bf16(wb2[0], wb2[1]); B10.y = pack_bf16(wb2[2], wb2[3]);
  B10.z = pack_bf16(wb2[4], wb2[5]); B10.w = pack_bf16(wb2[6], wb2[7]);
  B11.x = pack_bf16(wb2[8], wb2[9]); B11.y = pack_bf16(wb2[10], wb2[11]);
  B11.z = pack_bf16(wb2[12], wb2[13]); B11.w = pack_bf16(wb2[14], wb2[15]);
  Bt[lane * 4 + 0] = B00;
  Bt[lane * 4 + 1] = B01;
  Bt[lane * 4 + 2] = B10;
  Bt[lane * 4 + 3] = B11;
}

// ---------------- edge scorer (MFMA over K=64-padded 41 features) -----------
// wave = 16 edges. B fragments precomputed (k_sprep): 4 b128 loads/thread.
__global__ __launch_bounds__(256)
void k_score(const float* __restrict__ emb, const int* __restrict__ te,
             const float* __restrict__ PI, const uint4* __restrict__ Bt,
             const float* __restrict__ l1b, const float* __restrict__ lW,
             const float* __restrict__ lb, float* __restrict__ out, int ned) {
  int tid = threadIdx.x;
  int lane = tid & 63, w = tid >> 6;
  int lr = lane & 15, lg = lane >> 4;
  int e0w = blockIdx.x * 64 + w * 16;
  int e = e0w + lr;
  int ec = (e < ned) ? e : 0;

  uint4 B00 = Bt[lane * 4 + 0];
  uint4 B01 = Bt[lane * 4 + 1];
  uint4 B10 = Bt[lane * 4 + 2];
  uint4 B11 = Bt[lane * 4 + 3];

  // ---- A fragments for this lane's edge ----
  uint4 A0 = {0u, 0u, 0u, 0u}, A1 = {0u, 0u, 0u, 0u};
  const float* pie = PI + (size_t)ec * 25;
  if (lg < 2) {
    int2 uv = *(const int2*)(te + 2 * (size_t)ec);
    const float* eu = emb + (size_t)uv.x * H2 + lg * 8;
    const float* ev = emb + (size_t)uv.y * H2 + lg * 8;
    float4 a0 = *(const float4*)(eu);
    float4 a1 = *(const float4*)(eu + 4);
    float4 b0 = *(const float4*)(ev);
    float4 b1 = *(const float4*)(ev + 4);
    float d0 = a0.x - b0.x, d1 = a0.y - b0.y, d2 = a0.z - b0.z, d3 = a0.w - b0.w;
    float d4 = a1.x - b1.x, d5 = a1.y - b1.y, d6 = a1.z - b1.z, d7 = a1.w - b1.w;
    A0.x = pack_bf16(d0 * d0, d1 * d1);
    A0.y = pack_bf16(d2 * d2, d3 * d3);
    A0.z = pack_bf16(d4 * d4, d5 * d5);
    A0.w = pack_bf16(d6 * d6, d7 * d7);
    if (lg == 0) {  // a1: k=32..39 -> PI[16..23]
      f32x4a p0 = *(const f32x4a*)(pie + 16);
      f32x4a p1 = *(const f32x4a*)(pie + 20);
      A1.x = pack_bf16(p0[0], p0[1]); A1.y = pack_bf16(p0[2], p0[3]);
      A1.z = pack_bf16(p1[0], p1[1]); A1.w = pack_bf16(p1[2], p1[3]);
    } else {        // a1: k=40 -> PI[24], rest 0
      A1.x = pack_bf16(pie[24], 0.f);
    }
  } else if (lg == 2) {  // a0: k=16..23 -> PI[0..7]
    f32x4a p0 = *(const f32x4a*)(pie);
    f32x4a p1 = *(const f32x4a*)(pie + 4);
    A0.x = pack_bf16(p0[0], p0[1]); A0.y = pack_bf16(p0[2], p0[3]);
    A0.z = pack_bf16(p1[0], p1[1]); A0.w = pack_bf16(p1[2], p1[3]);
  } else {               // a0: k=24..31 -> PI[8..15]
    f32x4a p0 = *(const f32x4a*)(pie + 8);
    f32x4a p1 = *(const f32x4a*)(pie + 12);
    A0.x = pack_bf16(p0[0], p0[1]); A0.y = pack_bf16(p0[2], p0[3]);
    A0.z = pack_bf16(p1[0], p1[1]); A0.w = pack_bf16(p1[2], p1[3]);
  }

  f32x4 acc0 = {0.f, 0.f, 0.f, 0.f}, acc1 = {0.f, 0.f, 0.f, 0.f};
  acc0 = __builtin_amdgcn_mfma_f32_16x16x32_bf16(*(bf16x8*)&A0, *(bf16x8*)&B00, acc0, 0, 0, 0);
  acc0 = __builtin_amdgcn_mfma_f32_16x16x32_bf16(*(bf16x8*)&A1, *(bf16x8*)&B01, acc0, 0, 0, 0);
  acc1 = __builtin_amdgcn_mfma_f32_16x16x32_bf16(*(bf16x8*)&A0, *(bf16x8*)&B10, acc1, 0, 0, 0);
  acc1 = __builtin_amdgcn_mfma_f32_16x16x32_bf16(*(bf16x8*)&A1, *(bf16x8*)&B11, acc1, 0, 0, 0);

  // ---- epilogue: leaky-relu + 2nd layer, reduce over j (lr lanes) ----
  int j1 = 16 + lr;
  float bj0 = l1b[lr];
  float wj0 = lW[lr];
  float bj1 = (j1 < 25) ? l1b[j1] : 0.f;
  float wj1 = (j1 < 25) ? lW[j1] : 0.f;
  float lbv = lb[0];
  float part[4];
#pragma unroll
  for (int r = 0; r < 4; r++) {
    float a0v = acc0[r] + bj0;
    a0v = (a0v > 0.f) ? a0v : 0.2f * a0v;
    float a1v = acc1[r] + bj1;
    a1v = (a1v > 0.f) ? a1v : 0.2f * a1v;
    part[r] = a0v * wj0 + ((j1 < 25) ? a1v * wj1 : 0.f);
  }
#pragma unroll
  for (int r = 0; r < 4; r++) {
    part[r] += __shfl_xor(part[r], 1, 64);
    part[r] += __shfl_xor(part[r], 2, 64);
    part[r] += __shfl_xor(part[r], 4, 64);
    part[r] += __shfl_xor(part[r], 8, 64);
  }
  if (lr == 0) {
#pragma unroll
    for (int r = 0; r < 4; r++) {
      int eo = e0w + lg * 4 + r;
      if (eo < ned) {
        float s = fminf(fabsf(part[r] + lbv), 40.f);
        float z = 2.f - s;
        out[eo] = 1.f / (1.f + __expf(-z));
      }
    }
  }
}

// ---------------- launch -----------------------------------------------------
extern "C" void kernel_launch(void* const* d_in, const int* in_sizes, int n_in,
                              void* d_out, int out_size, void* d_ws, size_t ws_size,
                              hipStream_t stream) {
  const float* x   = (const float*)d_in[0];
  const int*   ei  = (const int*)d_in[1];
  const int*   te  = (const int*)d_in[2];
  const float* PI  = (const float*)d_in[3];
  const float* W1  = (const float*)d_in[4];
  const float* b1  = (const float*)d_in[5];
  const float* W2  = (const float*)d_in[6];
  const float* b2  = (const float*)d_in[7];
  const float* l1W = (const float*)d_in[8];
  const float* l1b = (const float*)d_in[9];
  const float* lW  = (const float*)d_in[10];
  const float* lb  = (const float*)d_in[11];
  float* out = (float*)d_out;

  int h1 = in_sizes[5];            // 100
  int F  = in_sizes[4] / h1;       // 256
  int N  = in_sizes[0] / F;        // 100000
  int E  = in_sizes[1] / 2;        // 1600000
  int ED = in_sizes[2] / 2;        // 1000000

  const int* src  = ei;
  const int* dstp = ei + E;

  int shift = 8;
  while ((((size_t)N + ((size_t)1 << shift) - 1) >> shift) > 512) shift++;
  int nbuc = (N + (1 << shift) - 1) >> shift;

  size_t off = 0;
  auto alloc = [&](size_t bytes) -> void* {
    void* p = (char*)d_ws + off;
    off += (bytes + 255) & ~(size_t)255;
    return p;
  };
  int*            deg      = (int*)alloc((size_t)N * 4);
  float*          dinv     = (float*)alloc((size_t)N * 4);
  int*            row_ptr  = (int*)alloc((size_t)(N + 1) * 4);
  int*            psum     = (int*)alloc(512 * 4);
  int*            bcnt     = (int*)alloc(512 * 4);
  int*            bbase    = (int*)alloc(520 * 4);
  int*            bfill    = (int*)alloc(512 * 4);
  int*            col_src  = (int*)alloc((size_t)E * 4);
  unsigned short* W1bf     = (unsigned short*)alloc((size_t)NPAD * FDIM * 2);
  uint4*          Bt       = (uint4*)alloc(64 * 4 * 16);
  unsigned*       t1p      = (unsigned*)alloc((size_t)N * 50 * 4);  // bf16 x2 packed
  unsigned*       h        = (unsigned*)alloc((size_t)N * 50 * 4);
  unsigned*       t2p      = (unsigned*)alloc((size_t)N * 8 * 4);
  float*          emb      = (float*)alloc((size_t)N * H2 * 4);

  int* tdst = (int*)h;             // temp binned edges alias h (dead until agg1)
  int* tsrc = (int*)h + E;

  int nb = (N + 255) / 256;
  int nwb = (E + BINCH - 1) / BINCH;

  hipMemsetAsync(bcnt, 0, 512 * 4, stream);
  k_bincnt<<<nwb, 256, 0, stream>>>(dstp, bcnt, E, shift);
  k_bscan<<<1, 512, 0, stream>>>(bcnt, bbase, bfill, nbuc, E);
  k_binwrite<<<nwb, 256, 0, stream>>>(src, dstp, bfill, tsrc, tdst, E, shift);
  k_deg2<<<nbuc, 256, 0, stream>>>(tdst, bbase, deg, dinv, N, shift);
  k_scanA<<<nb, 256, 0, stream>>>(deg, row_ptr, psum, N);
  k_scanB<<<1, 512, 0, stream>>>(psum, nb);
  k_scanC<<<nb, 256, 0, stream>>>(row_ptr, psum, N, E);
  k_csr2<<<nbuc, 256, 0, stream>>>(tsrc, tdst, bbase, row_ptr, col_src, N, shift);
  k_w1cast<<<(NPAD * FDIM + 255) / 256, 256, 0, stream>>>(W1, W1bf);
  k_sprep<<<1, 64, 0, stream>>>(l1W, Bt);
  k_gemm1m<<<(N + 127) / 128, 512, 0, stream>>>(x, W1bf, dinv, (unsigned short*)t1p, N);
  k_agg1<<<(int)(((size_t)N * 64 + 255) / 256), 256, 0, stream>>>(t1p, row_ptr, col_src, dinv, b1, h, N);
  k_gemm2<<<(N + 63) / 64, 256, 0, stream>>>(h, W2, dinv, t2p, N);
  k_agg2<<<(int)(((size_t)N * 64 + 255) / 256), 256, 0, stream>>>(t2p, row_ptr, col_src, dinv, b2, emb, N);
  k_score<<<(ED + 63) / 64, 256, 0, stream>>>(emb, te, PI, Bt, l1b, lW, lb, out, ED);
}

// Round 9
// 294.053 us; speedup vs baseline: 1.4127x; 1.0413x over previous
//
#include <hip/hip_runtime.h>
#include <hip/hip_bf16.h>
#include <math.h>

#define H1 100
#define H2 16
#define FDIM 256
#define NPAD 112   // H1 padded to 7*16
#define BINCH 4096 // edges per binning workgroup

typedef __attribute__((ext_vector_type(8))) short bf16x8;
typedef __attribute__((ext_vector_type(4))) float f32x4;

// ---- bf16 pack/unpack helpers (bit-exact unpack, RNE pack) ----
__device__ __forceinline__ float bf_lo(unsigned u) { return __uint_as_float(u << 16); }
__device__ __forceinline__ float bf_hi(unsigned u) { return __uint_as_float(u & 0xffff0000u); }
__device__ __forceinline__ unsigned f2bf_bits(float f) {
  unsigned x = __float_as_uint(f);
  return (x + 0x7fffu + ((x >> 16) & 1u)) >> 16;   // round-nearest-even
}
__device__ __forceinline__ unsigned pack_bf16(float a, float b) {
  return f2bf_bits(a) | (f2bf_bits(b) << 16);
}

// ============ CSR build via bucket binning ==========
__global__ __launch_bounds__(256)
void k_bincnt(const int* __restrict__ dst, int* __restrict__ bucket_cnt,
              int E, int shift) {
  __shared__ int lcnt[512];
  int t = threadIdx.x;
  for (int i = t; i < 512; i += 256) lcnt[i] = 0;
  __syncthreads();
  int base = blockIdx.x * BINCH;
#pragma unroll
  for (int i = 0; i < 16; i++) {
    int e = base + t + i * 256;
    if (e < E) atomicAdd(&lcnt[dst[e] >> shift], 1);
  }
  __syncthreads();
  for (int b = t; b < 512; b += 256) {
    int c = lcnt[b];
    if (c > 0) atomicAdd(&bucket_cnt[b], c);
  }
}

__global__ void k_bscan(const int* __restrict__ bucket_cnt, int* __restrict__ bucket_base,
                        int* __restrict__ bucket_fill, int nbuc, int E) {
  __shared__ int s[512];
  int tid = threadIdx.x;
  int v = (tid < nbuc) ? bucket_cnt[tid] : 0;
  s[tid] = v;
  __syncthreads();
  for (int off = 1; off < 512; off <<= 1) {
    int tt = (tid >= off) ? s[tid - off] : 0;
    __syncthreads();
    s[tid] += tt;
    __syncthreads();
  }
  if (tid < nbuc) { int ex = s[tid] - v; bucket_base[tid] = ex; bucket_fill[tid] = ex; }
  if (tid == 0) bucket_base[nbuc] = E;
}

__global__ __launch_bounds__(256)
void k_binwrite(const int* __restrict__ src, const int* __restrict__ dst,
                int* __restrict__ bucket_fill, int* __restrict__ tsrc,
                int* __restrict__ tdst, int E, int shift) {
  __shared__ int lcnt[512];
  __shared__ int loff[512];
  int t = threadIdx.x;
  for (int i = t; i < 512; i += 256) lcnt[i] = 0;
  __syncthreads();
  int base = blockIdx.x * BINCH;
  int d[16], s_[16];
#pragma unroll
  for (int i = 0; i < 16; i++) {
    int e = base + t + i * 256;
    if (e < E) {
      d[i] = dst[e]; s_[i] = src[e];
      atomicAdd(&lcnt[d[i] >> shift], 1);
    } else d[i] = -1;
  }
  __syncthreads();
  for (int b = t; b < 512; b += 256) {
    int c = lcnt[b];
    loff[b] = (c > 0) ? atomicAdd(&bucket_fill[b], c) : 0;
  }
  __syncthreads();
#pragma unroll
  for (int i = 0; i < 16; i++) {
    if (d[i] >= 0) {
      int p = atomicAdd(&loff[d[i] >> shift], 1);
      tdst[p] = d[i];
      tsrc[p] = s_[i];
    }
  }
}

__global__ __launch_bounds__(256)
void k_deg2(const int* __restrict__ tdst, const int* __restrict__ bucket_base,
            int* __restrict__ deg, float* __restrict__ dinv, int N, int shift) {
  __shared__ int lcnt[1024];
  int b = blockIdx.x, t = threadIdx.x;
  int bs = 1 << shift, mask = bs - 1;
  for (int i = t; i < bs; i += 256) lcnt[i] = 0;
  __syncthreads();
  int r0 = bucket_base[b], r1 = bucket_base[b + 1];
  for (int e = r0 + t; e < r1; e += 256) atomicAdd(&lcnt[tdst[e] & mask], 1);
  __syncthreads();
  for (int i = t; i < bs; i += 256) {
    int node = (b << shift) + i;
    if (node < N) {
      deg[node] = lcnt[i];
      dinv[node] = rsqrtf((float)(lcnt[i] + 1));  // +1 self-loop
    }
  }
}

__global__ __launch_bounds__(256)
void k_csr2(const int* __restrict__ tsrc, const int* __restrict__ tdst,
            const int* __restrict__ bucket_base, const int* __restrict__ row_ptr,
            int* __restrict__ col_src, int N, int shift) {
  __shared__ int lrp[1024];
  __shared__ int lfill[1024];
  int b = blockIdx.x, t = threadIdx.x;
  int bs = 1 << shift, mask = bs - 1;
  for (int i = t; i < bs; i += 256) {
    int node = (b << shift) + i;
    lrp[i] = row_ptr[node < N ? node : N];
    lfill[i] = 0;
  }
  __syncthreads();
  int r0 = bucket_base[b], r1 = bucket_base[b + 1];
  for (int e = r0 + t; e < r1; e += 256) {
    int dl = tdst[e] & mask;
    int p = lrp[dl] + atomicAdd(&lfill[dl], 1);
    col_src[p] = tsrc[e];
  }
}

// ---------------- exclusive scan over node degrees (3-phase) ----------------
__global__ void k_scanA(const int* __restrict__ deg, int* __restrict__ row_ptr,
                        int* __restrict__ psum, int n) {
  __shared__ int s[256];
  int tid = threadIdx.x;
  int i = blockIdx.x * 256 + tid;
  int v = (i < n) ? deg[i] : 0;
  s[tid] = v;
  __syncthreads();
  for (int off = 1; off < 256; off <<= 1) {
    int t = (tid >= off) ? s[tid - off] : 0;
    __syncthreads();
    s[tid] += t;
    __syncthreads();
  }
  if (i < n) row_ptr[i] = s[tid] - v;
  if (tid == 255) psum[blockIdx.x] = s[255];
}

__global__ void k_scanB(int* psum, int nb) {
  __shared__ int s[512];
  int tid = threadIdx.x;
  int v = (tid < nb) ? psum[tid] : 0;
  s[tid] = v;
  __syncthreads();
  for (int off = 1; off < 512; off <<= 1) {
    int t = (tid >= off) ? s[tid - off] : 0;
    __syncthreads();
    s[tid] += t;
    __syncthreads();
  }
  if (tid < nb) psum[tid] = s[tid] - v;
}

__global__ void k_scanC(int* row_ptr, const int* __restrict__ psum, int n, int E) {
  int i = blockIdx.x * blockDim.x + threadIdx.x;
  if (i < n) row_ptr[i] += psum[i >> 8];
  if (i == 0) row_ptr[n] = E;
}

// ------- W1 cast: W1bf[col][k] = bf16(W1[k][col]), padded to 112 cols -------
__global__ void k_w1cast(const float* __restrict__ W1, unsigned short* __restrict__ W1bf) {
  int i = blockIdx.x * 256 + threadIdx.x;
  if (i >= NPAD * FDIM) return;
  int col = i / FDIM, k = i % FDIM;
  float v = (col < H1) ? W1[k * H1 + col] : 0.f;
  W1bf[i] = (unsigned short)f2bf_bits(v);
}

// ------ GEMM1 (MFMA): t1p[r][c] = bf16( (x@W1)[r][c] * dinv[r] ) ------------
__global__ __launch_bounds__(512, 2)
void k_gemm1m(const float* __restrict__ x, const unsigned short* __restrict__ W1bf,
              const float* __restrict__ dinv, unsigned short* __restrict__ t1p, int n) {
  __shared__ unsigned short ws[NPAD * FDIM];   // [col][k] bf16, swizzled
  int tid = threadIdx.x;
  int lane = tid & 63, w = tid >> 6;
  int lr = lane & 15, lg = lane >> 4;
  int r0 = blockIdx.x * 128 + w * 16;
  int arow = r0 + lr;
  const float* xrow = x + (size_t)(arow < n ? arow : 0) * FDIM;

  // issue A loads first: 16 independent float4, in flight across the barrier
  float4 va[16];
#pragma unroll
  for (int s = 0; s < 8; ++s) {
    int kb = s * 32 + lg * 8;
    va[2 * s]     = *(const float4*)(xrow + kb);
    va[2 * s + 1] = *(const float4*)(xrow + kb + 4);
  }

  // stage W: 3584 16B-chunks, 7 per thread, swizzled
  for (int i = tid; i < NPAD * FDIM / 8; i += 512) {
    int col = i >> 5;          // 32 chunks per col
    int kc = i & 31;           // chunk = 8 k
    uint4 v = *(const uint4*)(W1bf + col * FDIM + kc * 8);
    unsigned addr = (unsigned)(col * 512 + kc * 16) ^ ((unsigned)(col & 7) << 4);
    *(uint4*)((char*)ws + addr) = v;
  }
  asm volatile("" ::: "memory");   // keep A loads issued above this point
  __syncthreads();

  bf16x8 af[8];
#pragma unroll
  for (int s = 0; s < 8; ++s) {
    uint4 au;
    au.x = pack_bf16(va[2 * s].x, va[2 * s].y);
    au.y = pack_bf16(va[2 * s].z, va[2 * s].w);
    au.z = pack_bf16(va[2 * s + 1].x, va[2 * s + 1].y);
    au.w = pack_bf16(va[2 * s + 1].z, va[2 * s + 1].w);
    af[s] = *(bf16x8*)&au;
  }

  f32x4 acc[7];
#pragma unroll
  for (int nt = 0; nt < 7; nt++) acc[nt] = (f32x4){0.f, 0.f, 0.f, 0.f};

#pragma unroll
  for (int s = 0; s < 8; ++s) {
    int kb = s * 32 + lg * 8;
#pragma unroll
    for (int nt = 0; nt < 7; nt++) {
      int col = nt * 16 + lr;
      unsigned addr = (unsigned)(col * 512 + kb * 2) ^ ((unsigned)(col & 7) << 4);
      bf16x8 b = *(bf16x8*)((char*)ws + addr);
      acc[nt] = __builtin_amdgcn_mfma_f32_16x16x32_bf16(af[s], b, acc[nt], 0, 0, 0);
    }
  }

  // epilogue: D col = lane&15, row = (lane>>4)*4 + r
  float dv[4];
  int rbase = r0 + lg * 4;
#pragma unroll
  for (int r = 0; r < 4; r++) dv[r] = (rbase + r < n) ? dinv[rbase + r] : 0.f;
#pragma unroll
  for (int nt = 0; nt < 7; nt++) {
    int col = nt * 16 + lr;
    if (col < H1) {
#pragma unroll
      for (int r = 0; r < 4; r++) {
        int row = rbase + r;
        if (row < n)
          t1p[(size_t)row * H1 + col] = (unsigned short)f2bf_bits(acc[nt][r] * dv[r]);
      }
    }
  }
}

// ---- agg1: h[d] = bf16(relu(dinv[d]*(sum t1p[s] + t1p[d]) + b1)) -----------
__global__ __launch_bounds__(256)
void k_agg1(const unsigned* __restrict__ t1p, const int* __restrict__ row_ptr,
            const int* __restrict__ col_src, const float* __restrict__ dinv,
            const float* __restrict__ b1, unsigned* __restrict__ h, int n) {
  int wid = (int)((blockIdx.x * (size_t)blockDim.x + threadIdx.x) >> 6);
  if (wid >= n) return;
  int lane = threadIdx.x & 63;
  if (lane >= 50) return;
  int beg = row_ptr[wid], end = row_ptr[wid + 1];
  float a0 = 0.f, a1 = 0.f;
  for (int e = beg; e < end; e += 8) {
    int last = end - 1;
    int i1 = e + 1 < end ? e + 1 : last;
    int i2 = e + 2 < end ? e + 2 : last;
    int i3 = e + 3 < end ? e + 3 : last;
    int i4 = e + 4 < end ? e + 4 : last;
    int i5 = e + 5 < end ? e + 5 : last;
    int i6 = e + 6 < end ? e + 6 : last;
    int i7 = e + 7 < end ? e + 7 : last;
    int s0 = col_src[e],  s1 = col_src[i1], s2 = col_src[i2], s3 = col_src[i3];
    int s4 = col_src[i4], s5 = col_src[i5], s6 = col_src[i6], s7 = col_src[i7];
    unsigned u0 = t1p[(size_t)s0 * 50 + lane];
    unsigned u1 = t1p[(size_t)s1 * 50 + lane];
    unsigned u2 = t1p[(size_t)s2 * 50 + lane];
    unsigned u3 = t1p[(size_t)s3 * 50 + lane];
    unsigned u4 = t1p[(size_t)s4 * 50 + lane];
    unsigned u5 = t1p[(size_t)s5 * 50 + lane];
    unsigned u6 = t1p[(size_t)s6 * 50 + lane];
    unsigned u7 = t1p[(size_t)s7 * 50 + lane];
    a0 += bf_lo(u0); a1 += bf_hi(u0);
    if (e + 1 < end) { a0 += bf_lo(u1); a1 += bf_hi(u1); }
    if (e + 2 < end) { a0 += bf_lo(u2); a1 += bf_hi(u2); }
    if (e + 3 < end) { a0 += bf_lo(u3); a1 += bf_hi(u3); }
    if (e + 4 < end) { a0 += bf_lo(u4); a1 += bf_hi(u4); }
    if (e + 5 < end) { a0 += bf_lo(u5); a1 += bf_hi(u5); }
    if (e + 6 < end) { a0 += bf_lo(u6); a1 += bf_hi(u6); }
    if (e + 7 < end) { a0 += bf_lo(u7); a1 += bf_hi(u7); }
  }
  unsigned su = t1p[(size_t)wid * 50 + lane];
  a0 += bf_lo(su);
  a1 += bf_hi(su);
  float dv = dinv[wid];
  float v0 = fmaxf(dv * a0 + b1[2 * lane], 0.f);
  float v1 = fmaxf(dv * a1 + b1[2 * lane + 1], 0.f);
  h[(size_t)wid * 50 + lane] = pack_bf16(v0, v1);
}

// ------ GEMM2: t2p = bf16( (h @ W2) * dinv )  (N x 100 x 16) ----------------
__global__ __launch_bounds__(256)
void k_gemm2(const unsigned* __restrict__ h, const float* __restrict__ W2,
             const float* __restrict__ dinv, unsigned* __restrict__ t2p, int n) {
  __shared__ alignas(16) float w2s[100][16];
  __shared__ float hs[64][101];
  int tid = threadIdx.x;
  int r0 = blockIdx.x * 64;
  for (int idx = tid; idx < H1 * H2; idx += 256) w2s[idx / 16][idx % 16] = W2[idx];
  for (int idx = tid; idx < 64 * 50; idx += 256) {
    int row = idx / 50, u = idx % 50;
    int gr = r0 + row;
    unsigned v = 0;
    if (gr < n) v = h[(size_t)gr * 50 + u];
    hs[row][2 * u + 0] = bf_lo(v);
    hs[row][2 * u + 1] = bf_hi(v);
  }
  __syncthreads();
  int r = tid & 63, cg = tid >> 6;
  float ax = 0.f, ay = 0.f, az = 0.f, aw = 0.f;
#pragma unroll 4
  for (int k = 0; k < H1; ++k) {
    float a = hs[r][k];
    float4 w = *(const float4*)&w2s[k][cg * 4];
    ax += a * w.x; ay += a * w.y; az += a * w.z; aw += a * w.w;
  }
  int gr = r0 + r;
  if (gr < n) {
    float dv = dinv[gr];
    unsigned u0 = pack_bf16(ax * dv, ay * dv);
    unsigned u1 = pack_bf16(az * dv, aw * dv);
    *(uint2*)(t2p + (size_t)gr * 8 + cg * 2) = make_uint2(u0, u1);
  }
}

// ------- agg2 + bias + relu + row-normalize: emb (N x 16, f32) --------------
__global__ __launch_bounds__(256)
void k_agg2(const unsigned* __restrict__ t2p, const int* __restrict__ row_ptr,
            const int* __restrict__ col_src, const float* __restrict__ dinv,
            const float* __restrict__ b2, float* __restrict__ emb, int n) {
  int wid = (int)((blockIdx.x * (size_t)blockDim.x + threadIdx.x) >> 6);
  if (wid >= n) return;
  int lane = threadIdx.x & 63;
  int es = lane >> 3, c = lane & 7;
  int beg = row_ptr[wid], end = row_ptr[wid + 1];
  float a0 = 0.f, a1 = 0.f;
  for (int e = beg + es; e < end; e += 8) {
    int s = col_src[e];
    unsigned u = t2p[(size_t)s * 8 + c];
    a0 += bf_lo(u);
    a1 += bf_hi(u);
  }
  a0 += __shfl_xor(a0, 8, 64);  a1 += __shfl_xor(a1, 8, 64);
  a0 += __shfl_xor(a0, 16, 64); a1 += __shfl_xor(a1, 16, 64);
  a0 += __shfl_xor(a0, 32, 64); a1 += __shfl_xor(a1, 32, 64);
  unsigned su = t2p[(size_t)wid * 8 + c];
  a0 += bf_lo(su);
  a1 += bf_hi(su);
  float dv = dinv[wid];
  float v0 = fmaxf(dv * a0 + b2[2 * c + 0], 0.f);
  float v1 = fmaxf(dv * a1 + b2[2 * c + 1], 0.f);
  float n2 = v0 * v0 + v1 * v1;
  n2 += __shfl_xor(n2, 1, 64);
  n2 += __shfl_xor(n2, 2, 64);
  n2 += __shfl_xor(n2, 4, 64);
  float scale = 1.f / fmaxf(sqrtf(n2), 1.f);
  if (es == 0) {
    *(float2*)(emb + (size_t)wid * H2 + 2 * c) = make_float2(v0 * scale, v1 * scale);
  }
}

// ---- scorer B-fragment precompute: one-time, 64 threads ----
__global__ void k_sprep(const float* __restrict__ l1W, uint4* __restrict__ Bt) {
  int lane = threadIdx.x;   // 0..63
  int lr = lane & 15, lg = lane >> 4;
  float wb[16];
#pragma unroll
  for (int i = 0; i < 8; i++) {
    int k0 = lg * 8 + i;
    wb[i] = (lr < 25) ? l1W[k0 * 25 + lr] : 0.f;
    int k1 = 32 + lg * 8 + i;
    wb[8 + i] = (lr < 25 && k1 < 41) ? l1W[k1 * 25 + lr] : 0.f;
  }
  int j1 = 16 + lr;
  float wb2[16];
#pragma unroll
  for (int i = 0; i < 8; i++) {
    int k0 = lg * 8 + i;
    wb2[i] = (j1 < 25) ? l1W[k0 * 25 + j1] : 0.f;
    int k1 = 32 + lg * 8 + i;
    wb2[8 + i] = (j1 < 25 && k1 < 41) ? l1W[k1 * 25 + j1] : 0.f;
  }
  uint4 B00, B01, B10, B11;
  B00.x = pack_bf16(wb[0], wb[1]);  B00.y = pack_bf16(wb[2], wb[3]);
  B00.z = pack_bf16(wb[4], wb[5]);  B00.w = pack_bf16(wb[6], wb[7]);
  B01.x = pack_bf16(wb[8], wb[9]);  B01.y = pack_bf16(wb[10], wb[11]);
  B01.z = pack_bf16(wb[12], wb[13]); B01.w = pack_bf16(wb[14], wb[15]);
  B10.x = pack_bf16(wb2[0], wb2[1]); B10.y = pack_bf16(wb2[2], wb2[3]);
  B10.z = pack_bf16(wb2[4], wb2[5]); B10.w = pack_bf16(wb2[6], wb2[7]);
  B11.x = pack_bf16(wb2[8], wb2[9]); B11.y = pack_bf16(wb2[10], wb2[11]);
  B11.z = pack_bf16(wb2[12], wb2[13]); B11.w = pack_bf16(wb2[14], wb2[15]);
  Bt[lane * 4 + 0] = B00;
  Bt[lane * 4 + 1] = B01;
  Bt[lane * 4 + 2] = B10;
  Bt[lane * 4 + 3] = B11;
}

// ---------------- edge scorer v3: LDS-staged PI, 256 edges/block ------------
// Block stages its contiguous 25.6KB PI slab coalesced; wave does 4x 16-edge
// MFMA iterations; B frags + epilogue constants loaded once per thread.
__global__ __launch_bounds__(256)
void k_score(const float* __restrict__ emb, const int* __restrict__ te,
             const float* __restrict__ PI, const uint4* __restrict__ Bt,
             const float* __restrict__ l1b, const float* __restrict__ lW,
             const float* __restrict__ lb, float* __restrict__ out, int ned) {
  __shared__ float lds_pi[256 * 25];   // 25.6 KB
  int tid = threadIdx.x;
  int lane = tid & 63, w = tid >> 6;
  int lr = lane & 15, lg = lane >> 4;
  int eb0 = blockIdx.x * 256;

  // ---- stage PI slab: 1600 aligned float4, 7 per thread ----
  {
    int base = eb0 * 25;               // float index; *4B multiple of 16 ✓
    int tot = ned * 25;
#pragma unroll
    for (int it = 0; it < 7; ++it) {
      int p4 = tid + it * 256;
      if (p4 < 1600) {
        int gp = base + p4 * 4;
        float4 v = make_float4(0.f, 0.f, 0.f, 0.f);
        if (gp + 4 <= tot) {
          v = *(const float4*)(PI + gp);
        } else {
          float* vp = (float*)&v;
          for (int k = 0; k < 4; k++) if (gp + k < tot) vp[k] = PI[gp + k];
        }
        *(float4*)&lds_pi[p4 * 4] = v;
      }
    }
  }
  __syncthreads();

  // ---- per-thread constants (reused over 4 iterations) ----
  uint4 B00 = Bt[lane * 4 + 0];
  uint4 B01 = Bt[lane * 4 + 1];
  uint4 B10 = Bt[lane * 4 + 2];
  uint4 B11 = Bt[lane * 4 + 3];
  int j1 = 16 + lr;
  float bj0 = l1b[lr];
  float wj0 = lW[lr];
  float bj1 = (j1 < 25) ? l1b[j1] : 0.f;
  float wj1 = (j1 < 25) ? lW[j1] : 0.f;
  float lbv = lb[0];

#pragma unroll
  for (int it = 0; it < 4; ++it) {
    int el = w * 64 + it * 16 + lr;    // local edge 0..255
    int ge = eb0 + el;
    int ec = (ge < ned) ? ge : (ned - 1);
    const float* pie = &lds_pi[el * 25];

    uint4 A0 = {0u, 0u, 0u, 0u}, A1 = {0u, 0u, 0u, 0u};
    if (lg < 2) {
      // sqdist slice k = lg*8 .. lg*8+7 (emb gather), + A1 PI slice from LDS
      int2 uv = *(const int2*)(te + 2 * (size_t)ec);
      const float* eu = emb + (size_t)uv.x * H2 + lg * 8;
      const float* ev = emb + (size_t)uv.y * H2 + lg * 8;
      float4 a0 = *(const float4*)(eu);
      float4 a1 = *(const float4*)(eu + 4);
      float4 b0 = *(const float4*)(ev);
      float4 b1 = *(const float4*)(ev + 4);
      float d0 = a0.x - b0.x, d1 = a0.y - b0.y, d2 = a0.z - b0.z, d3 = a0.w - b0.w;
      float d4 = a1.x - b1.x, d5 = a1.y - b1.y, d6 = a1.z - b1.z, d7 = a1.w - b1.w;
      A0.x = pack_bf16(d0 * d0, d1 * d1);
      A0.y = pack_bf16(d2 * d2, d3 * d3);
      A0.z = pack_bf16(d4 * d4, d5 * d5);
      A0.w = pack_bf16(d6 * d6, d7 * d7);
      if (lg == 0) {  // A1 k=32..39 -> PI[16..23]
        A1.x = pack_bf16(pie[16], pie[17]);
        A1.y = pack_bf16(pie[18], pie[19]);
        A1.z = pack_bf16(pie[20], pie[21]);
        A1.w = pack_bf16(pie[22], pie[23]);
      } else {        // A1 k=40 -> PI[24]
        A1.x = pack_bf16(pie[24], 0.f);
      }
    } else {
      // A0 PI slice: lg2 -> PI[0..7], lg3 -> PI[8..15]
      const float* pp = pie + (lg - 2) * 8;
      A0.x = pack_bf16(pp[0], pp[1]);
      A0.y = pack_bf16(pp[2], pp[3]);
      A0.z = pack_bf16(pp[4], pp[5]);
      A0.w = pack_bf16(pp[6], pp[7]);
    }

    f32x4 acc0 = {0.f, 0.f, 0.f, 0.f}, acc1 = {0.f, 0.f, 0.f, 0.f};
    acc0 = __builtin_amdgcn_mfma_f32_16x16x32_bf16(*(bf16x8*)&A0, *(bf16x8*)&B00, acc0, 0, 0, 0);
    acc0 = __builtin_amdgcn_mfma_f32_16x16x32_bf16(*(bf16x8*)&A1, *(bf16x8*)&B01, acc0, 0, 0, 0);
    acc1 = __builtin_amdgcn_mfma_f32_16x16x32_bf16(*(bf16x8*)&A0, *(bf16x8*)&B10, acc1, 0, 0, 0);
    acc1 = __builtin_amdgcn_mfma_f32_16x16x32_bf16(*(bf16x8*)&A1, *(bf16x8*)&B11, acc1, 0, 0, 0);

    float part[4];
#pragma unroll
    for (int r = 0; r < 4; r++) {
      float a0v = acc0[r] + bj0;
      a0v = (a0v > 0.f) ? a0v : 0.2f * a0v;
      float a1v = acc1[r] + bj1;
      a1v = (a1v > 0.f) ? a1v : 0.2f * a1v;
      part[r] = a0v * wj0 + ((j1 < 25) ? a1v * wj1 : 0.f);
    }
#pragma unroll
    for (int r = 0; r < 4; r++) {
      part[r] += __shfl_xor(part[r], 1, 64);
      part[r] += __shfl_xor(part[r], 2, 64);
      part[r] += __shfl_xor(part[r], 4, 64);
      part[r] += __shfl_xor(part[r], 8, 64);
    }
    if (lr == 0) {
#pragma unroll
      for (int r = 0; r < 4; r++) {
        int eo = eb0 + w * 64 + it * 16 + lg * 4 + r;
        if (eo < ned) {
          float s = fminf(fabsf(part[r] + lbv), 40.f);
          float z = 2.f - s;
          out[eo] = 1.f / (1.f + __expf(-z));
        }
      }
    }
  }
}

// ---------------- launch -----------------------------------------------------
extern "C" void kernel_launch(void* const* d_in, const int* in_sizes, int n_in,
                              void* d_out, int out_size, void* d_ws, size_t ws_size,
                              hipStream_t stream) {
  const float* x   = (const float*)d_in[0];
  const int*   ei  = (const int*)d_in[1];
  const int*   te  = (const int*)d_in[2];
  const float* PI  = (const float*)d_in[3];
  const float* W1  = (const float*)d_in[4];
  const float* b1  = (const float*)d_in[5];
  const float* W2  = (const float*)d_in[6];
  const float* b2  = (const float*)d_in[7];
  const float* l1W = (const float*)d_in[8];
  const float* l1b = (const float*)d_in[9];
  const float* lW  = (const float*)d_in[10];
  const float* lb  = (const float*)d_in[11];
  float* out = (float*)d_out;

  int h1 = in_sizes[5];            // 100
  int F  = in_sizes[4] / h1;       // 256
  int N  = in_sizes[0] / F;        // 100000
  int E  = in_sizes[1] / 2;        // 1600000
  int ED = in_sizes[2] / 2;        // 1000000

  const int* src  = ei;
  const int* dstp = ei + E;

  int shift = 8;
  while ((((size_t)N + ((size_t)1 << shift) - 1) >> shift) > 512) shift++;
  int nbuc = (N + (1 << shift) - 1) >> shift;

  size_t off = 0;
  auto alloc = [&](size_t bytes) -> void* {
    void* p = (char*)d_ws + off;
    off += (bytes + 255) & ~(size_t)255;
    return p;
  };
  int*            deg      = (int*)alloc((size_t)N * 4);
  float*          dinv     = (float*)alloc((size_t)N * 4);
  int*            row_ptr  = (int*)alloc((size_t)(N + 1) * 4);
  int*            psum     = (int*)alloc(512 * 4);
  int*            bcnt     = (int*)alloc(512 * 4);
  int*            bbase    = (int*)alloc(520 * 4);
  int*            bfill    = (int*)alloc(512 * 4);
  int*            col_src  = (int*)alloc((size_t)E * 4);
  unsigned short* W1bf     = (unsigned short*)alloc((size_t)NPAD * FDIM * 2);
  uint4*          Bt       = (uint4*)alloc(64 * 4 * 16);
  unsigned*       t1p      = (unsigned*)alloc((size_t)N * 50 * 4);  // bf16 x2 packed
  unsigned*       h        = (unsigned*)alloc((size_t)N * 50 * 4);
  unsigned*       t2p      = (unsigned*)alloc((size_t)N * 8 * 4);
  float*          emb      = (float*)alloc((size_t)N * H2 * 4);

  int* tdst = (int*)h;             // temp binned edges alias h (dead until agg1)
  int* tsrc = (int*)h + E;

  int nb = (N + 255) / 256;
  int nwb = (E + BINCH - 1) / BINCH;

  hipMemsetAsync(bcnt, 0, 512 * 4, stream);
  k_bincnt<<<nwb, 256, 0, stream>>>(dstp, bcnt, E, shift);
  k_bscan<<<1, 512, 0, stream>>>(bcnt, bbase, bfill, nbuc, E);
  k_binwrite<<<nwb, 256, 0, stream>>>(src, dstp, bfill, tsrc, tdst, E, shift);
  k_deg2<<<nbuc, 256, 0, stream>>>(tdst, bbase, deg, dinv, N, shift);
  k_scanA<<<nb, 256, 0, stream>>>(deg, row_ptr, psum, N);
  k_scanB<<<1, 512, 0, stream>>>(psum, nb);
  k_scanC<<<nb, 256, 0, stream>>>(row_ptr, psum, N, E);
  k_csr2<<<nbuc, 256, 0, stream>>>(tsrc, tdst, bbase, row_ptr, col_src, N, shift);
  k_w1cast<<<(NPAD * FDIM + 255) / 256, 256, 0, stream>>>(W1, W1bf);
  k_sprep<<<1, 64, 0, stream>>>(l1W, Bt);
  k_gemm1m<<<(N + 127) / 128, 512, 0, stream>>>(x, W1bf, dinv, (unsigned short*)t1p, N);
  k_agg1<<<(int)(((size_t)N * 64 + 255) / 256), 256, 0, stream>>>(t1p, row_ptr, col_src, dinv, b1, h, N);
  k_gemm2<<<(N + 63) / 64, 256, 0, stream>>>(h, W2, dinv, t2p, N);
  k_agg2<<<(int)(((size_t)N * 64 + 255) / 256), 256, 0, stream>>>(t2p, row_ptr, col_src, dinv, b2, emb, N);
  k_score<<<(ED + 255) / 256, 256, 0, stream>>>(emb, te, PI, Bt, l1b, lW, lb, out, ED);
}